// Round 1
// baseline (734.414 us; speedup 1.0000x reference)
//
#include <hip/hip_runtime.h>
#include <math.h>

#define NB_ 3
#define B_ 4
#define N_ 1024
#define CQ_ 128
#define CKV_ 64
#define CP_ 16
#define H_ 4
#define D_ 32
#define R_ (B_*N_)
#define KW_ 128
#define RC_ (R_*CQ_)   // 524288

__device__ __forceinline__ float sigmoidf_(float x) {
    return 1.0f / (1.0f + __expf(-x));
}

// ---------------------------------------------------------------------------
// k_cond: all c-side (a-independent) work for ALL 3 blocks, once per call.
//   gA  = sigmoid(LN(c)*a_sg @ a_gw)      kA  = LN(c)*a_sg @ a_sw
//   gT  = sigmoid(LN(c)*t_sg @ t_gw)      kT2 = LN(c)*t_sg @ t_sw
//   asig= sigmoid(c @ a_wso + a_bso)      tsig= sigmoid(c @ t_wso + t_bso)
// grid (R/8, NB), 512 threads. Waves 0-5 each own one K=64 GEMV; direct
// global float4 writes (no LDS scratch).
// ---------------------------------------------------------------------------
__global__ __launch_bounds__(512, 4) void k_cond(
    const float* __restrict__ c,
    const float* __restrict__ a_sg, const float* __restrict__ a_gw,
    const float* __restrict__ a_sw, const float* __restrict__ a_wso,
    const float* __restrict__ a_bso,
    const float* __restrict__ t_sg, const float* __restrict__ t_gw,
    const float* __restrict__ t_sw, const float* __restrict__ t_wso,
    const float* __restrict__ t_bso,
    float* __restrict__ gA, float* __restrict__ kA,
    float* __restrict__ gT, float* __restrict__ kT2,
    float* __restrict__ asig, float* __restrict__ tsig)
{
    __shared__ float xs_s[3 * 544];    // SA @0, ST @544, CR @1088; rows 8x68
    const int t = threadIdx.x;
    const int blk = blockIdx.y;
    const int base = blockIdx.x * 8;

    {   // phase 1: LN(c) stats, one wave per row (all 8 waves busy)
        const int rloc = t >> 6, li = t & 63;
        const int row = base + rloc;
        const float cv = c[row * 64 + li];
        float cs = cv, css = cv * cv;
        #pragma unroll
        for (int m = 1; m < 64; m <<= 1) {
            cs += __shfl_xor(cs, m);
            css += __shfl_xor(css, m);
        }
        const float cm = cs * (1.0f / 64.0f);
        const float crs = rsqrtf(css * (1.0f / 64.0f) - cm * cm + 1e-5f);
        const float cn = (cv - cm) * crs;
        xs_s[rloc * 68 + li]         = cn * a_sg[blk * 64 + li];
        xs_s[544 + rloc * 68 + li]   = cn * t_sg[blk * 64 + li];
        xs_s[1088 + rloc * 68 + li]  = cv;
    }
    __syncthreads();

    const int wave = t >> 6, lane = t & 63;
    if (wave >= 6) return;
    const int ig = lane >> 4, jc = lane & 15;
    const int c0 = jc * 8;
    const int r0 = ig * 2, r1 = r0 + 1;

    const float* W; const float* xs; float* out;
    int dosig; const float* bias = nullptr;
    switch (wave) {
        case 0: W = a_gw;  xs = xs_s;        out = gA;   dosig = 1; break;
        case 1: W = a_sw;  xs = xs_s;        out = kA;   dosig = 0; break;
        case 2: W = t_gw;  xs = xs_s + 544;  out = gT;   dosig = 1; break;
        case 3: W = t_sw;  xs = xs_s + 544;  out = kT2;  dosig = 0; break;
        case 4: W = a_wso; xs = xs_s + 1088; out = asig; dosig = 1; bias = a_bso; break;
        default: W = t_wso; xs = xs_s + 1088; out = tsig; dosig = 1; bias = t_bso; break;
    }
    W += blk * (CKV_ * CQ_) + c0;
    out += (size_t)blk * RC_;

    float acc0[8], acc1[8];
    #pragma unroll
    for (int e = 0; e < 8; e++) { acc0[e] = 0.f; acc1[e] = 0.f; }
    #pragma unroll 2
    for (int kk = 0; kk < 64; kk += 4) {
        float4 x40 = *(const float4*)(xs + r0 * 68 + kk);
        float4 x41 = *(const float4*)(xs + r1 * 68 + kk);
        #pragma unroll
        for (int q = 0; q < 4; q++) {
            const float4 wlo = *(const float4*)(W + (kk + q) * 128);
            const float4 whi = *(const float4*)(W + (kk + q) * 128 + 4);
            const float xa = ((const float*)&x40)[q];
            const float xb = ((const float*)&x41)[q];
            acc0[0] += xa * wlo.x; acc0[1] += xa * wlo.y;
            acc0[2] += xa * wlo.z; acc0[3] += xa * wlo.w;
            acc0[4] += xa * whi.x; acc0[5] += xa * whi.y;
            acc0[6] += xa * whi.z; acc0[7] += xa * whi.w;
            acc1[0] += xb * wlo.x; acc1[1] += xb * wlo.y;
            acc1[2] += xb * wlo.z; acc1[3] += xb * wlo.w;
            acc1[4] += xb * whi.x; acc1[5] += xb * whi.y;
            acc1[6] += xb * whi.z; acc1[7] += xb * whi.w;
        }
    }
    if (bias) {
        #pragma unroll
        for (int e = 0; e < 8; e++) {
            const float bv = bias[blk * 128 + c0 + e];
            acc0[e] += bv; acc1[e] += bv;
        }
    }
    if (dosig) {
        #pragma unroll
        for (int e = 0; e < 8; e++) {
            acc0[e] = sigmoidf_(acc0[e]);
            acc1[e] = sigmoidf_(acc1[e]);
        }
    }
    float* o0 = out + (size_t)(base + r0) * 128 + c0;
    float* o1 = out + (size_t)(base + r1) * 128 + c0;
    *(float4*)(o0)     = make_float4(acc0[0], acc0[1], acc0[2], acc0[3]);
    *(float4*)(o0 + 4) = make_float4(acc0[4], acc0[5], acc0[6], acc0[7]);
    *(float4*)(o1)     = make_float4(acc1[0], acc1[1], acc1[2], acc1[3]);
    *(float4*)(o1 + 4) = make_float4(acc1[4], acc1[5], acc1[6], acc1[7]);
}

// ---------------------------------------------------------------------------
// k_pre (lean): LN(a) -> modulate with precomputed gA/kA/gT/kT2 -> K=128
// GEMMs (qkvg from AH, w1/w2 from TH) -> bm = silu(a1)*a2.
// grid = R/8 = 512 blocks, 512 threads. LDS 25 KB (was 40 KB), 3 barriers.
// ---------------------------------------------------------------------------
#define P_AN 0
#define P_TH 1056
#define P_SCR 2112
#define P_SMEM (2112 + 4160)

__global__ __launch_bounds__(512, 4) void k_pre(
    const float* __restrict__ a,
    const float* __restrict__ gA, const float* __restrict__ kA,
    const float* __restrict__ gT, const float* __restrict__ kT2,
    const float* __restrict__ wq, const float* __restrict__ bq,
    const float* __restrict__ wk, const float* __restrict__ wv,
    const float* __restrict__ wg,
    const float* __restrict__ w1, const float* __restrict__ w2,
    float* __restrict__ qh, float* __restrict__ kh,
    float* __restrict__ vh, float* __restrict__ gh,
    float* __restrict__ bm)
{
    __shared__ float smem[P_SMEM];
    const int t = threadIdx.x;
    const int base = blockIdx.x * 8;

    {   // phase 1: LN(a) stats, one wave per row
        const int rloc = t >> 6, li = t & 63;
        const int row = base + rloc;
        float2 av = *(const float2*)(a + row * 128 + li * 2);
        float s = av.x + av.y;
        float ss = av.x * av.x + av.y * av.y;
        #pragma unroll
        for (int m = 1; m < 64; m <<= 1) {
            s += __shfl_xor(s, m);
            ss += __shfl_xor(ss, m);
        }
        const float am = s * (1.0f / 128.0f);
        const float ars = rsqrtf(ss * (1.0f / 128.0f) - am * am + 1e-5f);
        smem[P_AN + rloc * 132 + li * 2]     = (av.x - am) * ars;
        smem[P_AN + rloc * 132 + li * 2 + 1] = (av.y - am) * ars;
    }
    __syncthreads();

    // phase 2: modulate -> ah (in place over AN), th
    #pragma unroll
    for (int i2 = 0; i2 < 2; i2++) {
        const int e = t + i2 * 512;
        const int r = e >> 7, cc = e & 127;
        const int idx = (base + r) * 128 + cc;
        const float an = smem[P_AN + r * 132 + cc];
        smem[P_AN + r * 132 + cc] = gA[idx] * an + kA[idx];
        smem[P_TH + r * 132 + cc] = gT[idx] * an + kT2[idx];
    }
    __syncthreads();

    const int wave = t >> 6;
    const int lane = t & 63;
    const int ig = lane >> 4;
    const int jc = lane & 15;
    const int c0 = jc * 8;
    const int r0 = ig * 2, r1 = ig * 2 + 1;

    // phase 3: K=128 GEMMs. waves 0-3: qkvg from AH; 4-7: w1/w2 from TH
    {
        const float* W;
        const float* xs;
        int ldw, sel2 = 0, cb = 0;
        if (wave < 4) {
            W = (wave == 0 ? wq : wave == 1 ? wk : wave == 2 ? wv : wg) + c0;
            xs = smem + P_AN;
            ldw = 128;
        } else {
            const int u = (wave - 4) * 128 + c0;
            sel2 = u >> 8; cb = u & 255;
            W = (sel2 ? w2 : w1) + cb;
            xs = smem + P_TH;
            ldw = 256;
        }
        float acc0[8], acc1[8];
        #pragma unroll
        for (int e = 0; e < 8; e++) {
            const float init = (wave == 0) ? bq[c0 + e] : 0.f;
            acc0[e] = init; acc1[e] = init;
        }
        #pragma unroll 2
        for (int kk = 0; kk < 128; kk += 4) {
            float4 x40 = *(const float4*)(xs + r0 * 132 + kk);
            float4 x41 = *(const float4*)(xs + r1 * 132 + kk);
            #pragma unroll
            for (int q = 0; q < 4; q++) {
                const float4 wlo = *(const float4*)(W + (kk + q) * ldw);
                const float4 whi = *(const float4*)(W + (kk + q) * ldw + 4);
                const float xa = ((const float*)&x40)[q];
                const float xb = ((const float*)&x41)[q];
                acc0[0] += xa * wlo.x; acc0[1] += xa * wlo.y;
                acc0[2] += xa * wlo.z; acc0[3] += xa * wlo.w;
                acc0[4] += xa * whi.x; acc0[5] += xa * whi.y;
                acc0[6] += xa * whi.z; acc0[7] += xa * whi.w;
                acc1[0] += xb * wlo.x; acc1[1] += xb * wlo.y;
                acc1[2] += xb * wlo.z; acc1[3] += xb * wlo.w;
                acc1[4] += xb * whi.x; acc1[5] += xb * whi.y;
                acc1[6] += xb * whi.z; acc1[7] += xb * whi.w;
            }
        }
        if (wave < 4) {
            float* dst = (wave == 0 ? qh : wave == 1 ? kh : wave == 2 ? vh : gh);
            if (wave == 3) {
                #pragma unroll
                for (int e = 0; e < 8; e++) {
                    acc0[e] = sigmoidf_(acc0[e]);
                    acc1[e] = sigmoidf_(acc1[e]);
                }
            }
            *(float4*)(dst + (base + r0) * 128 + c0)     = make_float4(acc0[0], acc0[1], acc0[2], acc0[3]);
            *(float4*)(dst + (base + r0) * 128 + c0 + 4) = make_float4(acc0[4], acc0[5], acc0[6], acc0[7]);
            *(float4*)(dst + (base + r1) * 128 + c0)     = make_float4(acc1[0], acc1[1], acc1[2], acc1[3]);
            *(float4*)(dst + (base + r1) * 128 + c0 + 4) = make_float4(acc1[4], acc1[5], acc1[6], acc1[7]);
        } else {
            float* bsc = smem + P_SCR + sel2 * 2080;
            *(float4*)(bsc + r0 * 260 + cb)     = make_float4(acc0[0], acc0[1], acc0[2], acc0[3]);
            *(float4*)(bsc + r0 * 260 + cb + 4) = make_float4(acc0[4], acc0[5], acc0[6], acc0[7]);
            *(float4*)(bsc + r1 * 260 + cb)     = make_float4(acc1[0], acc1[1], acc1[2], acc1[3]);
            *(float4*)(bsc + r1 * 260 + cb + 4) = make_float4(acc1[4], acc1[5], acc1[6], acc1[7]);
        }
    }
    __syncthreads();

    // phase 4: bm = silu(a1) * a2
    #pragma unroll
    for (int i2 = 0; i2 < 4; i2++) {
        const int e = t + i2 * 512;
        const int r = e >> 8, cc = e & 255;
        const float a1 = smem[P_SCR + r * 260 + cc];
        const float a2 = smem[P_SCR + 2080 + r * 260 + cc];
        bm[(base + r) * 256 + cc] = a1 * sigmoidf_(a1) * a2;
    }
}

// ---------------------------------------------------------------------------
// k_zbias: unchanged.
// ---------------------------------------------------------------------------
__global__ __launch_bounds__(256) void k_zbias(
    const float* __restrict__ p,
    const float* __restrict__ lnz_g, const float* __restrict__ lnz_b,
    const float* __restrict__ wb, float* __restrict__ zb)
{
    const int tid = blockIdx.x * 256 + threadIdx.x;
    const int kk = tid & 127;
    const int n = (tid >> 7) & 1023;
    const int b = tid >> 17;
    const int row = b * N_ + n;
    const int k = ((n >> 5) << 5) - 48 + kk;

    if (k < 0 || k >= N_) {
        #pragma unroll
        for (int blk = 0; blk < NB_; blk++) {
            float* zo = zb + ((size_t)(blk * R_ + row) * H_) * KW_ + kk;
            #pragma unroll
            for (int h = 0; h < H_; h++) zo[h * KW_] = -1e10f;
        }
        return;
    }
    const float* pp = p + ((size_t)row * N_ + k) * CP_;
    float pv[16];
    float4 p0 = *(const float4*)(pp);
    float4 p1 = *(const float4*)(pp + 4);
    float4 p2 = *(const float4*)(pp + 8);
    float4 p3 = *(const float4*)(pp + 12);
    pv[0]=p0.x; pv[1]=p0.y; pv[2]=p0.z; pv[3]=p0.w;
    pv[4]=p1.x; pv[5]=p1.y; pv[6]=p1.z; pv[7]=p1.w;
    pv[8]=p2.x; pv[9]=p2.y; pv[10]=p2.z; pv[11]=p2.w;
    pv[12]=p3.x; pv[13]=p3.y; pv[14]=p3.z; pv[15]=p3.w;
    float s = 0.f, ss = 0.f;
    #pragma unroll
    for (int i = 0; i < 16; i++) { s += pv[i]; ss += pv[i] * pv[i]; }
    const float m = s * (1.0f / 16.0f);
    const float rs = rsqrtf(ss * (1.0f / 16.0f) - m * m + 1e-5f);

    #pragma unroll
    for (int blk = 0; blk < NB_; blk++) {
        const float* g = lnz_g + blk * 16;
        const float* bb = lnz_b + blk * 16;
        const float* w = wb + blk * 64;
        float z0 = 0.f, z1 = 0.f, z2 = 0.f, z3 = 0.f;
        #pragma unroll
        for (int cp = 0; cp < 16; cp++) {
            const float val = (pv[cp] - m) * rs * g[cp] + bb[cp];
            z0 += val * w[cp * 4 + 0];
            z1 += val * w[cp * 4 + 1];
            z2 += val * w[cp * 4 + 2];
            z3 += val * w[cp * 4 + 3];
        }
        float* zo = zb + ((size_t)(blk * R_ + row) * H_) * KW_ + kk;
        zo[0] = z0; zo[KW_] = z1; zo[2 * KW_] = z2; zo[3 * KW_] = z3;
    }
}

// ---------------------------------------------------------------------------
// k_attn: 32 queries x 128-key window. grid (32, H, B), 256 threads.
// Round-1 changes: float4 staging; key-ownership remap (g4*32 + j*4) makes
// QK ds_read_b128 conflict-free (was 4-way: 64B j-spacing aliases mod 32
// banks); full unroll of the d-loop pins qf in registers (no scratch);
// float4 softmax-weight writes; PV float4-weights, unroll 4; post-softmax
// block barrier replaced by wave-local lgkmcnt(0) (wsm roundtrip is
// intra-wave: both QK and PV use q = t>>3).
// ---------------------------------------------------------------------------
__global__ __launch_bounds__(256, 2) void k_attn(
    const float* __restrict__ qh, const float* __restrict__ kh,
    const float* __restrict__ vh, const float* __restrict__ gh,
    const float* __restrict__ zb, float* __restrict__ og)
{
    __shared__ float kT[32][136];
    __shared__ float vs[128][36];
    __shared__ float wsm[32][132];

    const int t = threadIdx.x;
    const int qb = blockIdx.x, h = blockIdx.y, b = blockIdx.z;
    const int k0 = qb * 32 - 48;

    // staging: 1024 float4 per array, 4 iters
    #pragma unroll
    for (int i = 0; i < 4; i++) {
        const int e = t + i * 256;
        const int kk = e >> 3, d4 = (e & 7) * 4;
        const int kg = k0 + kk;
        float4 kv = make_float4(0.f, 0.f, 0.f, 0.f);
        float4 vv = make_float4(0.f, 0.f, 0.f, 0.f);
        if (kg >= 0 && kg < N_) {
            const int addr = (b * N_ + kg) * 128 + h * 32 + d4;
            kv = *(const float4*)(kh + addr);
            vv = *(const float4*)(vh + addr);
        }
        kT[d4 + 0][kk] = kv.x;
        kT[d4 + 1][kk] = kv.y;
        kT[d4 + 2][kk] = kv.z;
        kT[d4 + 3][kk] = kv.w;
        *(float4*)&vs[kk][d4] = vv;
    }

    const int q = t >> 3, j = t & 7;
    const int n = qb * 32 + q;
    const float* qrow = qh + (b * N_ + n) * 128 + h * 32;
    float4 qf[8];
    #pragma unroll
    for (int dq = 0; dq < 8; dq++) qf[dq] = *(const float4*)(qrow + dq * 4);
    const float* zrow = zb + ((size_t)(b * N_ + n) * H_ + h) * KW_;
    float4 zf[4];
    #pragma unroll
    for (int g4 = 0; g4 < 4; g4++) zf[g4] = *(const float4*)(zrow + g4 * 32 + j * 4);
    __syncthreads();

    float4 acc[4];
    #pragma unroll
    for (int g4 = 0; g4 < 4; g4++) acc[g4] = make_float4(0.f, 0.f, 0.f, 0.f);
    const float* qfs = (const float*)qf;
    #pragma unroll
    for (int d = 0; d < 32; d++) {   // full unroll: d compile-time -> qf in regs
        const float qd = qfs[d];
        #pragma unroll
        for (int g4 = 0; g4 < 4; g4++) {
            const float4 k4 = *(const float4*)&kT[d][g4 * 32 + j * 4];
            acc[g4].x += qd * k4.x; acc[g4].y += qd * k4.y;
            acc[g4].z += qd * k4.z; acc[g4].w += qd * k4.w;
        }
    }
    const float scale = 0.1767766952966369f;
    float fr[16];
    #pragma unroll
    for (int g4 = 0; g4 < 4; g4++) {
        fr[g4*4+0] = zf[g4].x + acc[g4].x * scale;
        fr[g4*4+1] = zf[g4].y + acc[g4].y * scale;
        fr[g4*4+2] = zf[g4].z + acc[g4].z * scale;
        fr[g4*4+3] = zf[g4].w + acc[g4].w * scale;
    }
    float mx = fr[0];
    #pragma unroll
    for (int i = 1; i < 16; i++) mx = fmaxf(mx, fr[i]);
    #pragma unroll
    for (int mk = 1; mk < 8; mk <<= 1) mx = fmaxf(mx, __shfl_xor(mx, mk));
    float sum = 0.f;
    #pragma unroll
    for (int i = 0; i < 16; i++) { fr[i] = __expf(fr[i] - mx); sum += fr[i]; }
    #pragma unroll
    for (int mk = 1; mk < 8; mk <<= 1) sum += __shfl_xor(sum, mk);
    const float rinv = 1.0f / sum;
    #pragma unroll
    for (int g4 = 0; g4 < 4; g4++) {
        *(float4*)&wsm[q][g4 * 32 + j * 4] = make_float4(
            fr[g4*4+0] * rinv, fr[g4*4+1] * rinv,
            fr[g4*4+2] * rinv, fr[g4*4+3] * rinv);
    }
    // wsm written and read by the SAME wave (q = t>>3 in both phases):
    // wave-local LDS drain instead of a block barrier.
    asm volatile("s_waitcnt lgkmcnt(0)" ::: "memory");

    // PV: o[q][j*4..j*4+3] over 128 keys, float4 weights
    const int addrO = (b * N_ + n) * 128 + h * 32 + j * 4;
    const float4 g4v = *(const float4*)(gh + addrO);   // prefetch gate
    float4 o = make_float4(0.f, 0.f, 0.f, 0.f);
    #pragma unroll 4
    for (int kk = 0; kk < 128; kk += 4) {
        const float4 w4 = *(const float4*)&wsm[q][kk];
        const float4 v0 = *(const float4*)&vs[kk + 0][j * 4];
        const float4 v1 = *(const float4*)&vs[kk + 1][j * 4];
        const float4 v2 = *(const float4*)&vs[kk + 2][j * 4];
        const float4 v3 = *(const float4*)&vs[kk + 3][j * 4];
        o.x += w4.x * v0.x + w4.y * v1.x + w4.z * v2.x + w4.w * v3.x;
        o.y += w4.x * v0.y + w4.y * v1.y + w4.z * v2.y + w4.w * v3.y;
        o.z += w4.x * v0.z + w4.y * v1.z + w4.z * v2.z + w4.w * v3.z;
        o.w += w4.x * v0.w + w4.y * v1.w + w4.z * v2.w + w4.w * v3.w;
    }
    float4 outv;
    outv.x = o.x * g4v.x; outv.y = o.y * g4v.y;
    outv.z = o.z * g4v.z; outv.w = o.w * g4v.w;
    *(float4*)(og + addrO) = outv;
}

// ---------------------------------------------------------------------------
// k_combine: out = asig*(og@wo) + tsig*(bm@wout). Unchanged except unroll.
// ---------------------------------------------------------------------------
__global__ __launch_bounds__(256, 4) void k_combine(
    const float* __restrict__ og, const float* __restrict__ bm,
    const float* __restrict__ wo, const float* __restrict__ wout,
    const float* __restrict__ asig, const float* __restrict__ tsig,
    float* __restrict__ out)
{
    __shared__ float scr[4 * 1056];
    const int t = threadIdx.x;
    const int base = blockIdx.x * 8;
    const int wave = t >> 6, lane = t & 63;
    const int ig = lane >> 4, jc = lane & 15;
    const int c0 = jc * 8;
    const int r0 = ig * 2, r1 = ig * 2 + 1;

    float acc0[8], acc1[8];
    #pragma unroll
    for (int e = 0; e < 8; e++) { acc0[e] = 0.f; acc1[e] = 0.f; }

    if (wave < 2) {
        const float* W = wo + c0;
        const float* X = og + base * 128;
        const int kbeg = wave * 64;
        #pragma unroll 2
        for (int kk = kbeg; kk < kbeg + 64; kk += 4) {
            float4 x40 = *(const float4*)(X + r0 * 128 + kk);
            float4 x41 = *(const float4*)(X + r1 * 128 + kk);
            #pragma unroll
            for (int q = 0; q < 4; q++) {
                const float4 wlo = *(const float4*)(W + (kk + q) * 128);
                const float4 whi = *(const float4*)(W + (kk + q) * 128 + 4);
                const float xa = ((const float*)&x40)[q];
                const float xb = ((const float*)&x41)[q];
                acc0[0] += xa * wlo.x; acc0[1] += xa * wlo.y;
                acc0[2] += xa * wlo.z; acc0[3] += xa * wlo.w;
                acc0[4] += xa * whi.x; acc0[5] += xa * whi.y;
                acc0[6] += xa * whi.z; acc0[7] += xa * whi.w;
                acc1[0] += xb * wlo.x; acc1[1] += xb * wlo.y;
                acc1[2] += xb * wlo.z; acc1[3] += xb * wlo.w;
                acc1[4] += xb * whi.x; acc1[5] += xb * whi.y;
                acc1[6] += xb * whi.z; acc1[7] += xb * whi.w;
            }
        }
    } else {
        const float* W = wout + c0;
        const float* X = bm + base * 256;
        const int kbeg = (wave - 2) * 128;
        #pragma unroll 2
        for (int kk = kbeg; kk < kbeg + 128; kk += 4) {
            float4 x40 = *(const float4*)(X + r0 * 256 + kk);
            float4 x41 = *(const float4*)(X + r1 * 256 + kk);
            #pragma unroll
            for (int q = 0; q < 4; q++) {
                const float4 wlo = *(const float4*)(W + (kk + q) * 128);
                const float4 whi = *(const float4*)(W + (kk + q) * 128 + 4);
                const float xa = ((const float*)&x40)[q];
                const float xb = ((const float*)&x41)[q];
                acc0[0] += xa * wlo.x; acc0[1] += xa * wlo.y;
                acc0[2] += xa * wlo.z; acc0[3] += xa * wlo.w;
                acc0[4] += xa * whi.x; acc0[5] += xa * whi.y;
                acc0[6] += xa * whi.z; acc0[7] += xa * whi.w;
                acc1[0] += xb * wlo.x; acc1[1] += xb * wlo.y;
                acc1[2] += xb * wlo.z; acc1[3] += xb * wlo.w;
                acc1[4] += xb * whi.x; acc1[5] += xb * whi.y;
                acc1[6] += xb * whi.z; acc1[7] += xb * whi.w;
            }
        }
    }
    float* sc = scr + wave * 1056;
    *(float4*)(sc + r0 * 132 + c0)     = make_float4(acc0[0], acc0[1], acc0[2], acc0[3]);
    *(float4*)(sc + r0 * 132 + c0 + 4) = make_float4(acc0[4], acc0[5], acc0[6], acc0[7]);
    *(float4*)(sc + r1 * 132 + c0)     = make_float4(acc1[0], acc1[1], acc1[2], acc1[3]);
    *(float4*)(sc + r1 * 132 + c0 + 4) = make_float4(acc1[4], acc1[5], acc1[6], acc1[7]);
    __syncthreads();

    #pragma unroll
    for (int i2 = 0; i2 < 4; i2++) {
        const int e = t + i2 * 256;
        const int r = e >> 7, cc = e & 127;
        const float* s = scr + r * 132 + cc;
        const int idx = (base + r) * 128 + cc;
        out[idx] = asig[idx] * (s[0] + s[1056]) + tsig[idx] * (s[2112] + s[3168]);
    }
}

// ---------------------------------------------------------------------------
extern "C" void kernel_launch(void* const* d_in, const int* in_sizes, int n_in,
                              void* d_out, int out_size, void* d_ws, size_t ws_size,
                              hipStream_t stream)
{
    const float* q        = (const float*)d_in[0];
    const float* c        = (const float*)d_in[1];
    const float* p        = (const float*)d_in[2];
    const float* a_sg_all = (const float*)d_in[3];
    const float* a_gw_all = (const float*)d_in[4];
    const float* a_sw_all = (const float*)d_in[5];
    const float* wq_all   = (const float*)d_in[6];
    const float* bq_all   = (const float*)d_in[7];
    const float* wk_all   = (const float*)d_in[8];
    const float* wv_all   = (const float*)d_in[9];
    const float* lnzg_all = (const float*)d_in[10];
    const float* lnzb_all = (const float*)d_in[11];
    const float* wb_all   = (const float*)d_in[12];
    const float* wgt_all  = (const float*)d_in[13];
    const float* wo_all   = (const float*)d_in[14];
    const float* awso_all = (const float*)d_in[15];
    const float* abso_all = (const float*)d_in[16];
    const float* t_sg_all = (const float*)d_in[17];
    const float* t_gw_all = (const float*)d_in[18];
    const float* t_sw_all = (const float*)d_in[19];
    const float* w1_all   = (const float*)d_in[20];
    const float* w2_all   = (const float*)d_in[21];
    const float* wout_all = (const float*)d_in[22];
    const float* twso_all = (const float*)d_in[23];
    const float* tbso_all = (const float*)d_in[24];

    float* ws = (float*)d_ws;
    const size_t RC = (size_t)RC_;        // 524288
    float* qh    = ws;
    float* kh    = ws + RC;
    float* vh    = ws + 2 * RC;
    float* gh    = ws + 3 * RC;
    float* bmb   = ws + 4 * RC;           // 2 RC
    float* ogb   = ws + 6 * RC;
    float* abuf  = ws + 7 * RC;
    float* zbb   = ws + 8 * RC;           // NB*R*H*KW = 12 RC
    float* gAb   = ws + 20 * RC;          // 3 RC each from here
    float* kAb   = ws + 23 * RC;
    float* gTb   = ws + 26 * RC;
    float* kT2b  = ws + 29 * RC;
    float* asigb = ws + 32 * RC;
    float* tsigb = ws + 35 * RC;          // ends at 38 RC ≈ 80 MB

    k_zbias<<<dim3(B_ * N_ * KW_ / 256), dim3(256), 0, stream>>>(
        p, lnzg_all, lnzb_all, wb_all, zbb);

    k_cond<<<dim3(R_ / 8, NB_), dim3(512), 0, stream>>>(
        c, a_sg_all, a_gw_all, a_sw_all, awso_all, abso_all,
        t_sg_all, t_gw_all, t_sw_all, twso_all, tbso_all,
        gAb, kAb, gTb, kT2b, asigb, tsigb);

    const float* acur = q;
    for (int blk = 0; blk < NB_; blk++) {
        k_pre<<<dim3(R_ / 8), dim3(512), 0, stream>>>(
            acur,
            gAb + (size_t)blk * RC, kAb + (size_t)blk * RC,
            gTb + (size_t)blk * RC, kT2b + (size_t)blk * RC,
            wq_all + blk * CQ_ * CQ_, bq_all + blk * CQ_,
            wk_all + blk * CQ_ * CQ_, wv_all + blk * CQ_ * CQ_,
            wgt_all + blk * CQ_ * CQ_,
            w1_all + blk * CQ_ * 2 * CQ_, w2_all + blk * CQ_ * 2 * CQ_,
            qh, kh, vh, gh, bmb);
        k_attn<<<dim3(N_ / 32, H_, B_), dim3(256), 0, stream>>>(
            qh, kh, vh, gh, zbb + (size_t)blk * R_ * H_ * KW_, ogb);
        float* outp = (blk == NB_ - 1) ? (float*)d_out : abuf;
        k_combine<<<dim3(R_ / 8), dim3(256), 0, stream>>>(
            ogb, bmb, wo_all + blk * CQ_ * CQ_, wout_all + blk * 2 * CQ_ * CQ_,
            asigb + (size_t)blk * RC, tsigb + (size_t)blk * RC, outp);
        acur = abuf;
    }
}

// Round 2
// 631.186 us; speedup vs baseline: 1.1635x; 1.1635x over previous
//
#include <hip/hip_runtime.h>
#include <math.h>

#define NB_ 3
#define B_ 4
#define N_ 1024
#define CQ_ 128
#define CKV_ 64
#define CP_ 16
#define H_ 4
#define D_ 32
#define R_ (B_*N_)
#define KW_ 128

__device__ __forceinline__ float sigmoidf_(float x) {
    return 1.0f / (1.0f + __expf(-x));
}

// ---------------------------------------------------------------------------
// k_pre: fused AdaLN (attn+trans) + qkvg projections + transition silu-mul.
// grid = R/8 = 512 blocks, 512 threads (8 waves). 8 rows per block.
// (baseline structure — reverted from the round-1 k_cond split, which added
// a 60 MB global round-trip and an exposed-latency phase: 646->734 regression)
// ---------------------------------------------------------------------------
#define AN_OFF 0
#define SA_OFF 1056
#define ST_OFF 1600
#define CR_OFF 2144
#define TH_OFF 2688
#define SCR_OFF 3744
#define SMEM_F (3744 + 6336)

__global__ __launch_bounds__(512, 4) void k_pre(
    const float* __restrict__ a, const float* __restrict__ c,
    const float* __restrict__ a_sg, const float* __restrict__ a_gw,
    const float* __restrict__ a_sw, const float* __restrict__ a_wso,
    const float* __restrict__ a_bso,
    const float* __restrict__ t_sg, const float* __restrict__ t_gw,
    const float* __restrict__ t_sw, const float* __restrict__ t_wso,
    const float* __restrict__ t_bso,
    const float* __restrict__ wq, const float* __restrict__ bq,
    const float* __restrict__ wk, const float* __restrict__ wv,
    const float* __restrict__ wg,
    const float* __restrict__ w1, const float* __restrict__ w2,
    float* __restrict__ qh, float* __restrict__ kh,
    float* __restrict__ vh, float* __restrict__ gh,
    float* __restrict__ bm,
    float* __restrict__ asig, float* __restrict__ tsig)
{
    __shared__ float smem[SMEM_F];
    const int t = threadIdx.x;
    const int base = blockIdx.x * 8;

    // ---- phase 1: LN stats, one wave per row ----
    {
        const int rloc = t >> 6, li = t & 63;
        const int row = base + rloc;
        float2 av = *(const float2*)(a + row * 128 + li * 2);
        float s = av.x + av.y;
        float ss = av.x * av.x + av.y * av.y;
        float cv = c[row * 64 + li];
        float cs = cv, css = cv * cv;
        #pragma unroll
        for (int m = 1; m < 64; m <<= 1) {
            s += __shfl_xor(s, m);
            ss += __shfl_xor(ss, m);
            cs += __shfl_xor(cs, m);
            css += __shfl_xor(css, m);
        }
        const float am = s * (1.0f / 128.0f);
        const float ars = rsqrtf(ss * (1.0f / 128.0f) - am * am + 1e-5f);
        const float cm = cs * (1.0f / 64.0f);
        const float crs = rsqrtf(css * (1.0f / 64.0f) - cm * cm + 1e-5f);
        smem[AN_OFF + rloc * 132 + li * 2]     = (av.x - am) * ars;
        smem[AN_OFF + rloc * 132 + li * 2 + 1] = (av.y - am) * ars;
        const float cn = (cv - cm) * crs;
        smem[SA_OFF + rloc * 68 + li] = cn * a_sg[li];
        smem[ST_OFF + rloc * 68 + li] = cn * t_sg[li];
        smem[CR_OFF + rloc * 68 + li] = cv;
    }
    __syncthreads();

    const int wave = t >> 6;
    const int lane = t & 63;
    const int ig = lane >> 4;       // row pair group 0..3
    const int jc = lane & 15;       // col group
    const int c0 = jc * 8;
    const int r0 = ig * 2, r1 = ig * 2 + 1;

    // ---- phase 2: six K=64 GEMVs, one matrix per wave (waves 0..5) ----
    if (wave < 6) {
        const float* W;
        const float* xs;
        switch (wave) {
            case 0: W = a_gw;  xs = smem + SA_OFF; break;
            case 1: W = a_sw;  xs = smem + SA_OFF; break;
            case 2: W = t_gw;  xs = smem + ST_OFF; break;
            case 3: W = t_sw;  xs = smem + ST_OFF; break;
            case 4: W = a_wso; xs = smem + CR_OFF; break;
            default: W = t_wso; xs = smem + CR_OFF; break;
        }
        W += c0;
        float acc0[8], acc1[8];
        #pragma unroll
        for (int e = 0; e < 8; e++) { acc0[e] = 0.f; acc1[e] = 0.f; }
        for (int kk = 0; kk < 64; kk += 4) {
            float4 x40 = *(const float4*)(xs + r0 * 68 + kk);
            float4 x41 = *(const float4*)(xs + r1 * 68 + kk);
            #pragma unroll
            for (int q = 0; q < 4; q++) {
                const float4 wlo = *(const float4*)(W + (kk + q) * 128);
                const float4 whi = *(const float4*)(W + (kk + q) * 128 + 4);
                const float xa = ((const float*)&x40)[q];
                const float xb = ((const float*)&x41)[q];
                acc0[0] += xa * wlo.x; acc0[1] += xa * wlo.y;
                acc0[2] += xa * wlo.z; acc0[3] += xa * wlo.w;
                acc0[4] += xa * whi.x; acc0[5] += xa * whi.y;
                acc0[6] += xa * whi.z; acc0[7] += xa * whi.w;
                acc1[0] += xb * wlo.x; acc1[1] += xb * wlo.y;
                acc1[2] += xb * wlo.z; acc1[3] += xb * wlo.w;
                acc1[4] += xb * whi.x; acc1[5] += xb * whi.y;
                acc1[6] += xb * whi.z; acc1[7] += xb * whi.w;
            }
        }
        float* sc = smem + SCR_OFF + wave * 1056;
        *(float4*)(sc + r0 * 132 + c0)     = make_float4(acc0[0], acc0[1], acc0[2], acc0[3]);
        *(float4*)(sc + r0 * 132 + c0 + 4) = make_float4(acc0[4], acc0[5], acc0[6], acc0[7]);
        *(float4*)(sc + r1 * 132 + c0)     = make_float4(acc1[0], acc1[1], acc1[2], acc1[3]);
        *(float4*)(sc + r1 * 132 + c0 + 4) = make_float4(acc1[4], acc1[5], acc1[6], acc1[7]);
    }
    __syncthreads();

    // ---- phase 3: combine -> ah (in-place over AN), th, asig/tsig ----
    #pragma unroll
    for (int i2 = 0; i2 < 2; i2++) {
        const int e = t + i2 * 512;       // 1024 entries: 8 rows x 128 cols
        const int r = e >> 7, cc = e & 127;
        const float* sc = smem + SCR_OFF + r * 132 + cc;
        const float anv = smem[AN_OFF + r * 132 + cc];
        const float ahv = sigmoidf_(sc[0]) * anv + sc[1056];
        const float thv = sigmoidf_(sc[2 * 1056]) * anv + sc[3 * 1056];
        smem[AN_OFF + r * 132 + cc] = ahv;
        smem[TH_OFF + r * 132 + cc] = thv;
        const int idx = (base + r) * 128 + cc;
        asig[idx] = sigmoidf_(sc[4 * 1056] + a_bso[cc]);
        tsig[idx] = sigmoidf_(sc[5 * 1056] + t_bso[cc]);
    }
    __syncthreads();

    // ---- phase 4: K=128 GEMMs. waves 0-3: qkvg from AH; 4-7: w1/w2 from TH ----
    {
        const float* W;
        const float* xs;
        int ldw, sel2 = 0, cb = 0;
        if (wave < 4) {
            W = (wave == 0 ? wq : wave == 1 ? wk : wave == 2 ? wv : wg) + c0;
            xs = smem + AN_OFF;
            ldw = 128;
        } else {
            const int u = (wave - 4) * 128 + c0;
            sel2 = u >> 8; cb = u & 255;
            W = (sel2 ? w2 : w1) + cb;
            xs = smem + TH_OFF;
            ldw = 256;
        }
        float acc0[8], acc1[8];
        #pragma unroll
        for (int e = 0; e < 8; e++) {
            const float init = (wave == 0) ? bq[c0 + e] : 0.f;
            acc0[e] = init; acc1[e] = init;
        }
        for (int kk = 0; kk < 128; kk += 4) {
            float4 x40 = *(const float4*)(xs + r0 * 132 + kk);
            float4 x41 = *(const float4*)(xs + r1 * 132 + kk);
            #pragma unroll
            for (int q = 0; q < 4; q++) {
                const float4 wlo = *(const float4*)(W + (kk + q) * ldw);
                const float4 whi = *(const float4*)(W + (kk + q) * ldw + 4);
                const float xa = ((const float*)&x40)[q];
                const float xb = ((const float*)&x41)[q];
                acc0[0] += xa * wlo.x; acc0[1] += xa * wlo.y;
                acc0[2] += xa * wlo.z; acc0[3] += xa * wlo.w;
                acc0[4] += xa * whi.x; acc0[5] += xa * whi.y;
                acc0[6] += xa * whi.z; acc0[7] += xa * whi.w;
                acc1[0] += xb * wlo.x; acc1[1] += xb * wlo.y;
                acc1[2] += xb * wlo.z; acc1[3] += xb * wlo.w;
                acc1[4] += xb * whi.x; acc1[5] += xb * whi.y;
                acc1[6] += xb * whi.z; acc1[7] += xb * whi.w;
            }
        }
        if (wave < 4) {
            float* dst = (wave == 0 ? qh : wave == 1 ? kh : wave == 2 ? vh : gh);
            if (wave == 3) {
                #pragma unroll
                for (int e = 0; e < 8; e++) {
                    acc0[e] = sigmoidf_(acc0[e]);
                    acc1[e] = sigmoidf_(acc1[e]);
                }
            }
            *(float4*)(dst + (base + r0) * 128 + c0)     = make_float4(acc0[0], acc0[1], acc0[2], acc0[3]);
            *(float4*)(dst + (base + r0) * 128 + c0 + 4) = make_float4(acc0[4], acc0[5], acc0[6], acc0[7]);
            *(float4*)(dst + (base + r1) * 128 + c0)     = make_float4(acc1[0], acc1[1], acc1[2], acc1[3]);
            *(float4*)(dst + (base + r1) * 128 + c0 + 4) = make_float4(acc1[4], acc1[5], acc1[6], acc1[7]);
        } else {
            float* bsc = smem + SCR_OFF + sel2 * 2080;
            *(float4*)(bsc + r0 * 260 + cb)     = make_float4(acc0[0], acc0[1], acc0[2], acc0[3]);
            *(float4*)(bsc + r0 * 260 + cb + 4) = make_float4(acc0[4], acc0[5], acc0[6], acc0[7]);
            *(float4*)(bsc + r1 * 260 + cb)     = make_float4(acc1[0], acc1[1], acc1[2], acc1[3]);
            *(float4*)(bsc + r1 * 260 + cb + 4) = make_float4(acc1[4], acc1[5], acc1[6], acc1[7]);
        }
    }
    __syncthreads();

    // ---- phase 4c: bm = silu(a1) * a2 ----
    #pragma unroll
    for (int i2 = 0; i2 < 4; i2++) {
        const int e = t + i2 * 512;       // 2048 = 8 rows x 256 cols
        const int r = e >> 8, cc = e & 255;
        const float a1 = smem[SCR_OFF + r * 260 + cc];
        const float a2 = smem[SCR_OFF + 2080 + r * 260 + cc];
        bm[(base + r) * 256 + cc] = a1 * sigmoidf_(a1) * a2;
    }
}

// ---------------------------------------------------------------------------
// k_zbias: z-bias for all 3 blocks in one pass. zb layout [NB][R][H][KW].
// ---------------------------------------------------------------------------
__global__ __launch_bounds__(256) void k_zbias(
    const float* __restrict__ p,
    const float* __restrict__ lnz_g, const float* __restrict__ lnz_b,
    const float* __restrict__ wb, float* __restrict__ zb)
{
    const int tid = blockIdx.x * 256 + threadIdx.x;
    const int kk = tid & 127;
    const int n = (tid >> 7) & 1023;
    const int b = tid >> 17;
    const int row = b * N_ + n;
    const int k = ((n >> 5) << 5) - 48 + kk;

    if (k < 0 || k >= N_) {
        #pragma unroll
        for (int blk = 0; blk < NB_; blk++) {
            float* zo = zb + ((size_t)(blk * R_ + row) * H_) * KW_ + kk;
            #pragma unroll
            for (int h = 0; h < H_; h++) zo[h * KW_] = -1e10f;
        }
        return;
    }
    const float* pp = p + ((size_t)row * N_ + k) * CP_;
    float pv[16];
    float4 p0 = *(const float4*)(pp);
    float4 p1 = *(const float4*)(pp + 4);
    float4 p2 = *(const float4*)(pp + 8);
    float4 p3 = *(const float4*)(pp + 12);
    pv[0]=p0.x; pv[1]=p0.y; pv[2]=p0.z; pv[3]=p0.w;
    pv[4]=p1.x; pv[5]=p1.y; pv[6]=p1.z; pv[7]=p1.w;
    pv[8]=p2.x; pv[9]=p2.y; pv[10]=p2.z; pv[11]=p2.w;
    pv[12]=p3.x; pv[13]=p3.y; pv[14]=p3.z; pv[15]=p3.w;
    float s = 0.f, ss = 0.f;
    #pragma unroll
    for (int i = 0; i < 16; i++) { s += pv[i]; ss += pv[i] * pv[i]; }
    const float m = s * (1.0f / 16.0f);
    const float rs = rsqrtf(ss * (1.0f / 16.0f) - m * m + 1e-5f);

    #pragma unroll
    for (int blk = 0; blk < NB_; blk++) {
        const float* g = lnz_g + blk * 16;
        const float* bb = lnz_b + blk * 16;
        const float* w = wb + blk * 64;
        float z0 = 0.f, z1 = 0.f, z2 = 0.f, z3 = 0.f;
        #pragma unroll
        for (int cp = 0; cp < 16; cp++) {
            const float val = (pv[cp] - m) * rs * g[cp] + bb[cp];
            z0 += val * w[cp * 4 + 0];
            z1 += val * w[cp * 4 + 1];
            z2 += val * w[cp * 4 + 2];
            z3 += val * w[cp * 4 + 3];
        }
        float* zo = zb + ((size_t)(blk * R_ + row) * H_) * KW_ + kk;
        zo[0] = z0; zo[KW_] = z1; zo[2 * KW_] = z2; zo[3 * KW_] = z3;
    }
}

// ---------------------------------------------------------------------------
// k_attn: 32 queries x 128-key window. grid (32, H, B), 256 threads.
// Kept from round 1 (correctness-verified, absmax identical to baseline):
//  - float4 staging (4x fewer global load instrs)
//  - key-ownership remap (g4*32 + j*4): QK ds_read_b128 conflict-free
//    (old j*16 spacing = 64 B aliased mod 32 banks -> 4-way conflict)
//  - full unroll of the d-loop pins qf in registers (no scratch)
//  - float4 softmax-weight writes; PV float4-weights, unroll 4
//  - post-softmax wave-local lgkmcnt(0) instead of block barrier (wsm
//    roundtrip is intra-wave: both QK and PV use q = t>>3)
// ---------------------------------------------------------------------------
__global__ __launch_bounds__(256) void k_attn(
    const float* __restrict__ qh, const float* __restrict__ kh,
    const float* __restrict__ vh, const float* __restrict__ gh,
    const float* __restrict__ zb, float* __restrict__ og)
{
    __shared__ float kT[32][136];
    __shared__ float vs[128][36];
    __shared__ float wsm[32][132];

    const int t = threadIdx.x;
    const int qb = blockIdx.x, h = blockIdx.y, b = blockIdx.z;
    const int k0 = qb * 32 - 48;

    // staging: 1024 float4 per array, 4 iters
    #pragma unroll
    for (int i = 0; i < 4; i++) {
        const int e = t + i * 256;
        const int kk = e >> 3, d4 = (e & 7) * 4;
        const int kg = k0 + kk;
        float4 kv = make_float4(0.f, 0.f, 0.f, 0.f);
        float4 vv = make_float4(0.f, 0.f, 0.f, 0.f);
        if (kg >= 0 && kg < N_) {
            const int addr = (b * N_ + kg) * 128 + h * 32 + d4;
            kv = *(const float4*)(kh + addr);
            vv = *(const float4*)(vh + addr);
        }
        kT[d4 + 0][kk] = kv.x;
        kT[d4 + 1][kk] = kv.y;
        kT[d4 + 2][kk] = kv.z;
        kT[d4 + 3][kk] = kv.w;
        *(float4*)&vs[kk][d4] = vv;
    }

    const int q = t >> 3, j = t & 7;
    const int n = qb * 32 + q;
    const float* qrow = qh + (b * N_ + n) * 128 + h * 32;
    float4 qf[8];
    #pragma unroll
    for (int dq = 0; dq < 8; dq++) qf[dq] = *(const float4*)(qrow + dq * 4);
    const float* zrow = zb + ((size_t)(b * N_ + n) * H_ + h) * KW_;
    float4 zf[4];
    #pragma unroll
    for (int g4 = 0; g4 < 4; g4++) zf[g4] = *(const float4*)(zrow + g4 * 32 + j * 4);
    __syncthreads();

    float4 acc[4];
    #pragma unroll
    for (int g4 = 0; g4 < 4; g4++) acc[g4] = make_float4(0.f, 0.f, 0.f, 0.f);
    const float* qfs = (const float*)qf;
    #pragma unroll
    for (int d = 0; d < 32; d++) {   // full unroll: d compile-time -> qf in regs
        const float qd = qfs[d];
        #pragma unroll
        for (int g4 = 0; g4 < 4; g4++) {
            const float4 k4 = *(const float4*)&kT[d][g4 * 32 + j * 4];
            acc[g4].x += qd * k4.x; acc[g4].y += qd * k4.y;
            acc[g4].z += qd * k4.z; acc[g4].w += qd * k4.w;
        }
    }
    const float scale = 0.1767766952966369f;
    float fr[16];
    #pragma unroll
    for (int g4 = 0; g4 < 4; g4++) {
        fr[g4*4+0] = zf[g4].x + acc[g4].x * scale;
        fr[g4*4+1] = zf[g4].y + acc[g4].y * scale;
        fr[g4*4+2] = zf[g4].z + acc[g4].z * scale;
        fr[g4*4+3] = zf[g4].w + acc[g4].w * scale;
    }
    float mx = fr[0];
    #pragma unroll
    for (int i = 1; i < 16; i++) mx = fmaxf(mx, fr[i]);
    #pragma unroll
    for (int mk = 1; mk < 8; mk <<= 1) mx = fmaxf(mx, __shfl_xor(mx, mk));
    float sum = 0.f;
    #pragma unroll
    for (int i = 0; i < 16; i++) { fr[i] = __expf(fr[i] - mx); sum += fr[i]; }
    #pragma unroll
    for (int mk = 1; mk < 8; mk <<= 1) sum += __shfl_xor(sum, mk);
    const float rinv = 1.0f / sum;
    #pragma unroll
    for (int g4 = 0; g4 < 4; g4++) {
        *(float4*)&wsm[q][g4 * 32 + j * 4] = make_float4(
            fr[g4*4+0] * rinv, fr[g4*4+1] * rinv,
            fr[g4*4+2] * rinv, fr[g4*4+3] * rinv);
    }
    // wsm written and read by the SAME wave (q = t>>3 in both phases):
    // wave-local LDS drain instead of a block barrier.
    asm volatile("s_waitcnt lgkmcnt(0)" ::: "memory");

    // PV: o[q][j*4..j*4+3] over 128 keys, float4 weights
    const int addrO = (b * N_ + n) * 128 + h * 32 + j * 4;
    const float4 g4v = *(const float4*)(gh + addrO);   // prefetch gate
    float4 o = make_float4(0.f, 0.f, 0.f, 0.f);
    #pragma unroll 4
    for (int kk = 0; kk < 128; kk += 4) {
        const float4 w4 = *(const float4*)&wsm[q][kk];
        const float4 v0 = *(const float4*)&vs[kk + 0][j * 4];
        const float4 v1 = *(const float4*)&vs[kk + 1][j * 4];
        const float4 v2 = *(const float4*)&vs[kk + 2][j * 4];
        const float4 v3 = *(const float4*)&vs[kk + 3][j * 4];
        o.x += w4.x * v0.x + w4.y * v1.x + w4.z * v2.x + w4.w * v3.x;
        o.y += w4.x * v0.y + w4.y * v1.y + w4.z * v2.y + w4.w * v3.y;
        o.z += w4.x * v0.z + w4.y * v1.z + w4.z * v2.z + w4.w * v3.z;
        o.w += w4.x * v0.w + w4.y * v1.w + w4.z * v2.w + w4.w * v3.w;
    }
    float4 outv;
    outv.x = o.x * g4v.x; outv.y = o.y * g4v.y;
    outv.z = o.z * g4v.z; outv.w = o.w * g4v.w;
    *(float4*)(og + addrO) = outv;
}

// ---------------------------------------------------------------------------
// k_combine: out = asig*(og@wo) + tsig*(bm@wout).
// grid = R/8 = 512, block = 256 (4 waves, K-split: w0/w1 halve wo-K, w2/w3
// halve wout-K), partials exchanged via LDS. (baseline, no unroll pragma)
// ---------------------------------------------------------------------------
__global__ __launch_bounds__(256, 4) void k_combine(
    const float* __restrict__ og, const float* __restrict__ bm,
    const float* __restrict__ wo, const float* __restrict__ wout,
    const float* __restrict__ asig, const float* __restrict__ tsig,
    float* __restrict__ out)
{
    __shared__ float scr[4 * 1056];
    const int t = threadIdx.x;
    const int base = blockIdx.x * 8;
    const int wave = t >> 6, lane = t & 63;
    const int ig = lane >> 4, jc = lane & 15;
    const int c0 = jc * 8;
    const int r0 = ig * 2, r1 = ig * 2 + 1;

    float acc0[8], acc1[8];
    #pragma unroll
    for (int e = 0; e < 8; e++) { acc0[e] = 0.f; acc1[e] = 0.f; }

    if (wave < 2) {
        const float* W = wo + c0;
        const float* X = og + base * 128;
        const int kbeg = wave * 64;
        for (int kk = kbeg; kk < kbeg + 64; kk += 4) {
            float4 x40 = *(const float4*)(X + r0 * 128 + kk);
            float4 x41 = *(const float4*)(X + r1 * 128 + kk);
            #pragma unroll
            for (int q = 0; q < 4; q++) {
                const float4 wlo = *(const float4*)(W + (kk + q) * 128);
                const float4 whi = *(const float4*)(W + (kk + q) * 128 + 4);
                const float xa = ((const float*)&x40)[q];
                const float xb = ((const float*)&x41)[q];
                acc0[0] += xa * wlo.x; acc0[1] += xa * wlo.y;
                acc0[2] += xa * wlo.z; acc0[3] += xa * wlo.w;
                acc0[4] += xa * whi.x; acc0[5] += xa * whi.y;
                acc0[6] += xa * whi.z; acc0[7] += xa * whi.w;
                acc1[0] += xb * wlo.x; acc1[1] += xb * wlo.y;
                acc1[2] += xb * wlo.z; acc1[3] += xb * wlo.w;
                acc1[4] += xb * whi.x; acc1[5] += xb * whi.y;
                acc1[6] += xb * whi.z; acc1[7] += xb * whi.w;
            }
        }
    } else {
        const float* W = wout + c0;
        const float* X = bm + base * 256;
        const int kbeg = (wave - 2) * 128;
        for (int kk = kbeg; kk < kbeg + 128; kk += 4) {
            float4 x40 = *(const float4*)(X + r0 * 256 + kk);
            float4 x41 = *(const float4*)(X + r1 * 256 + kk);
            #pragma unroll
            for (int q = 0; q < 4; q++) {
                const float4 wlo = *(const float4*)(W + (kk + q) * 128);
                const float4 whi = *(const float4*)(W + (kk + q) * 128 + 4);
                const float xa = ((const float*)&x40)[q];
                const float xb = ((const float*)&x41)[q];
                acc0[0] += xa * wlo.x; acc0[1] += xa * wlo.y;
                acc0[2] += xa * wlo.z; acc0[3] += xa * wlo.w;
                acc0[4] += xa * whi.x; acc0[5] += xa * whi.y;
                acc0[6] += xa * whi.z; acc0[7] += xa * whi.w;
                acc1[0] += xb * wlo.x; acc1[1] += xb * wlo.y;
                acc1[2] += xb * wlo.z; acc1[3] += xb * wlo.w;
                acc1[4] += xb * whi.x; acc1[5] += xb * whi.y;
                acc1[6] += xb * whi.z; acc1[7] += xb * whi.w;
            }
        }
    }
    float* sc = scr + wave * 1056;
    *(float4*)(sc + r0 * 132 + c0)     = make_float4(acc0[0], acc0[1], acc0[2], acc0[3]);
    *(float4*)(sc + r0 * 132 + c0 + 4) = make_float4(acc0[4], acc0[5], acc0[6], acc0[7]);
    *(float4*)(sc + r1 * 132 + c0)     = make_float4(acc1[0], acc1[1], acc1[2], acc1[3]);
    *(float4*)(sc + r1 * 132 + c0 + 4) = make_float4(acc1[4], acc1[5], acc1[6], acc1[7]);
    __syncthreads();

    #pragma unroll
    for (int i2 = 0; i2 < 4; i2++) {
        const int e = t + i2 * 256;       // 1024 = 8 rows x 128 cols
        const int r = e >> 7, cc = e & 127;
        const float* s = scr + r * 132 + cc;
        const int idx = (base + r) * 128 + cc;
        out[idx] = asig[idx] * (s[0] + s[1056]) + tsig[idx] * (s[2112] + s[3168]);
    }
}

// ---------------------------------------------------------------------------
extern "C" void kernel_launch(void* const* d_in, const int* in_sizes, int n_in,
                              void* d_out, int out_size, void* d_ws, size_t ws_size,
                              hipStream_t stream)
{
    const float* q        = (const float*)d_in[0];
    const float* c        = (const float*)d_in[1];
    const float* p        = (const float*)d_in[2];
    const float* a_sg_all = (const float*)d_in[3];
    const float* a_gw_all = (const float*)d_in[4];
    const float* a_sw_all = (const float*)d_in[5];
    const float* wq_all   = (const float*)d_in[6];
    const float* bq_all   = (const float*)d_in[7];
    const float* wk_all   = (const float*)d_in[8];
    const float* wv_all   = (const float*)d_in[9];
    const float* lnzg_all = (const float*)d_in[10];
    const float* lnzb_all = (const float*)d_in[11];
    const float* wb_all   = (const float*)d_in[12];
    const float* wgt_all  = (const float*)d_in[13];
    const float* wo_all   = (const float*)d_in[14];
    const float* awso_all = (const float*)d_in[15];
    const float* abso_all = (const float*)d_in[16];
    const float* t_sg_all = (const float*)d_in[17];
    const float* t_gw_all = (const float*)d_in[18];
    const float* t_sw_all = (const float*)d_in[19];
    const float* w1_all   = (const float*)d_in[20];
    const float* w2_all   = (const float*)d_in[21];
    const float* wout_all = (const float*)d_in[22];
    const float* twso_all = (const float*)d_in[23];
    const float* tbso_all = (const float*)d_in[24];

    float* ws = (float*)d_ws;
    const size_t RC = (size_t)R_ * CQ_;   // 524288
    float* qh   = ws;
    float* kh   = ws + RC;
    float* vh   = ws + 2 * RC;
    float* gh   = ws + 3 * RC;
    float* bmb  = ws + 4 * RC;            // R*256 = 2*RC
    float* asig = ws + 6 * RC;
    float* tsig = ws + 7 * RC;
    float* abuf = ws + 8 * RC;
    float* ogb  = ws + 9 * RC;
    float* zbb  = ws + 10 * RC;           // NB*R*H*KW = 12*RC

    k_zbias<<<dim3(B_ * N_ * KW_ / 256), dim3(256), 0, stream>>>(
        p, lnzg_all, lnzb_all, wb_all, zbb);

    const float* acur = q;
    for (int blk = 0; blk < NB_; blk++) {
        k_pre<<<dim3(R_ / 8), dim3(512), 0, stream>>>(
            acur, c,
            a_sg_all + blk * CKV_, a_gw_all + blk * CKV_ * CQ_,
            a_sw_all + blk * CKV_ * CQ_, awso_all + blk * CKV_ * CQ_,
            abso_all + blk * CQ_,
            t_sg_all + blk * CKV_, t_gw_all + blk * CKV_ * CQ_,
            t_sw_all + blk * CKV_ * CQ_, twso_all + blk * CKV_ * CQ_,
            tbso_all + blk * CQ_,
            wq_all + blk * CQ_ * CQ_, bq_all + blk * CQ_,
            wk_all + blk * CQ_ * CQ_, wv_all + blk * CQ_ * CQ_,
            wgt_all + blk * CQ_ * CQ_,
            w1_all + blk * CQ_ * 2 * CQ_, w2_all + blk * CQ_ * 2 * CQ_,
            qh, kh, vh, gh, bmb, asig, tsig);
        k_attn<<<dim3(N_ / 32, H_, B_), dim3(256), 0, stream>>>(
            qh, kh, vh, gh, zbb + (size_t)blk * R_ * H_ * KW_, ogb);
        float* outp = (blk == NB_ - 1) ? (float*)d_out : abuf;
        k_combine<<<dim3(R_ / 8), dim3(256), 0, stream>>>(
            ogb, bmb, wo_all + blk * CQ_ * CQ_, wout_all + blk * 2 * CQ_ * CQ_,
            asig, tsig, outp);
        acur = abuf;
    }
}

// Round 3
// 582.029 us; speedup vs baseline: 1.2618x; 1.0845x over previous
//
#include <hip/hip_runtime.h>
#include <math.h>

#define NB_ 3
#define B_ 4
#define N_ 1024
#define CQ_ 128
#define CKV_ 64
#define CP_ 16
#define H_ 4
#define D_ 32
#define R_ (B_*N_)
#define KW_ 128

__device__ __forceinline__ float sigmoidf_(float x) {
    return 1.0f / (1.0f + __expf(-x));
}

// ---------------------------------------------------------------------------
// k_pre: fused AdaLN (attn+trans) + qkvg projections + transition silu-mul.
// grid = R/8 = 512 blocks, 512 threads (8 waves). 8 rows per block.
// Used only for iteration 0 (a = q input). Iterations 1,2 use k_cpre.
// ---------------------------------------------------------------------------
#define AN_OFF 0
#define SA_OFF 1056
#define ST_OFF 1600
#define CR_OFF 2144
#define TH_OFF 2688
#define SCR_OFF 3744
#define SMEM_F (3744 + 6336)

__global__ __launch_bounds__(512, 4) void k_pre(
    const float* __restrict__ a, const float* __restrict__ c,
    const float* __restrict__ a_sg, const float* __restrict__ a_gw,
    const float* __restrict__ a_sw, const float* __restrict__ a_wso,
    const float* __restrict__ a_bso,
    const float* __restrict__ t_sg, const float* __restrict__ t_gw,
    const float* __restrict__ t_sw, const float* __restrict__ t_wso,
    const float* __restrict__ t_bso,
    const float* __restrict__ wq, const float* __restrict__ bq,
    const float* __restrict__ wk, const float* __restrict__ wv,
    const float* __restrict__ wg,
    const float* __restrict__ w1, const float* __restrict__ w2,
    float* __restrict__ qh, float* __restrict__ kh,
    float* __restrict__ vh, float* __restrict__ gh,
    float* __restrict__ bm,
    float* __restrict__ asig, float* __restrict__ tsig)
{
    __shared__ float smem[SMEM_F];
    const int t = threadIdx.x;
    const int base = blockIdx.x * 8;

    // ---- phase 1: LN stats, one wave per row ----
    {
        const int rloc = t >> 6, li = t & 63;
        const int row = base + rloc;
        float2 av = *(const float2*)(a + row * 128 + li * 2);
        float s = av.x + av.y;
        float ss = av.x * av.x + av.y * av.y;
        float cv = c[row * 64 + li];
        float cs = cv, css = cv * cv;
        #pragma unroll
        for (int m = 1; m < 64; m <<= 1) {
            s += __shfl_xor(s, m);
            ss += __shfl_xor(ss, m);
            cs += __shfl_xor(cs, m);
            css += __shfl_xor(css, m);
        }
        const float am = s * (1.0f / 128.0f);
        const float ars = rsqrtf(ss * (1.0f / 128.0f) - am * am + 1e-5f);
        const float cm = cs * (1.0f / 64.0f);
        const float crs = rsqrtf(css * (1.0f / 64.0f) - cm * cm + 1e-5f);
        smem[AN_OFF + rloc * 132 + li * 2]     = (av.x - am) * ars;
        smem[AN_OFF + rloc * 132 + li * 2 + 1] = (av.y - am) * ars;
        const float cn = (cv - cm) * crs;
        smem[SA_OFF + rloc * 68 + li] = cn * a_sg[li];
        smem[ST_OFF + rloc * 68 + li] = cn * t_sg[li];
        smem[CR_OFF + rloc * 68 + li] = cv;
    }
    __syncthreads();

    const int wave = t >> 6;
    const int lane = t & 63;
    const int ig = lane >> 4;       // row pair group 0..3
    const int jc = lane & 15;       // col group
    const int c0 = jc * 8;
    const int r0 = ig * 2, r1 = ig * 2 + 1;

    // ---- phase 2: six K=64 GEMVs, one matrix per wave (waves 0..5) ----
    if (wave < 6) {
        const float* W;
        const float* xs;
        switch (wave) {
            case 0: W = a_gw;  xs = smem + SA_OFF; break;
            case 1: W = a_sw;  xs = smem + SA_OFF; break;
            case 2: W = t_gw;  xs = smem + ST_OFF; break;
            case 3: W = t_sw;  xs = smem + ST_OFF; break;
            case 4: W = a_wso; xs = smem + CR_OFF; break;
            default: W = t_wso; xs = smem + CR_OFF; break;
        }
        W += c0;
        float acc0[8], acc1[8];
        #pragma unroll
        for (int e = 0; e < 8; e++) { acc0[e] = 0.f; acc1[e] = 0.f; }
        for (int kk = 0; kk < 64; kk += 4) {
            float4 x40 = *(const float4*)(xs + r0 * 68 + kk);
            float4 x41 = *(const float4*)(xs + r1 * 68 + kk);
            #pragma unroll
            for (int q = 0; q < 4; q++) {
                const float4 wlo = *(const float4*)(W + (kk + q) * 128);
                const float4 whi = *(const float4*)(W + (kk + q) * 128 + 4);
                const float xa = ((const float*)&x40)[q];
                const float xb = ((const float*)&x41)[q];
                acc0[0] += xa * wlo.x; acc0[1] += xa * wlo.y;
                acc0[2] += xa * wlo.z; acc0[3] += xa * wlo.w;
                acc0[4] += xa * whi.x; acc0[5] += xa * whi.y;
                acc0[6] += xa * whi.z; acc0[7] += xa * whi.w;
                acc1[0] += xb * wlo.x; acc1[1] += xb * wlo.y;
                acc1[2] += xb * wlo.z; acc1[3] += xb * wlo.w;
                acc1[4] += xb * whi.x; acc1[5] += xb * whi.y;
                acc1[6] += xb * whi.z; acc1[7] += xb * whi.w;
            }
        }
        float* sc = smem + SCR_OFF + wave * 1056;
        *(float4*)(sc + r0 * 132 + c0)     = make_float4(acc0[0], acc0[1], acc0[2], acc0[3]);
        *(float4*)(sc + r0 * 132 + c0 + 4) = make_float4(acc0[4], acc0[5], acc0[6], acc0[7]);
        *(float4*)(sc + r1 * 132 + c0)     = make_float4(acc1[0], acc1[1], acc1[2], acc1[3]);
        *(float4*)(sc + r1 * 132 + c0 + 4) = make_float4(acc1[4], acc1[5], acc1[6], acc1[7]);
    }
    __syncthreads();

    // ---- phase 3: combine -> ah (in-place over AN), th, asig/tsig ----
    #pragma unroll
    for (int i2 = 0; i2 < 2; i2++) {
        const int e = t + i2 * 512;       // 1024 entries: 8 rows x 128 cols
        const int r = e >> 7, cc = e & 127;
        const float* sc = smem + SCR_OFF + r * 132 + cc;
        const float anv = smem[AN_OFF + r * 132 + cc];
        const float ahv = sigmoidf_(sc[0]) * anv + sc[1056];
        const float thv = sigmoidf_(sc[2 * 1056]) * anv + sc[3 * 1056];
        smem[AN_OFF + r * 132 + cc] = ahv;
        smem[TH_OFF + r * 132 + cc] = thv;
        const int idx = (base + r) * 128 + cc;
        asig[idx] = sigmoidf_(sc[4 * 1056] + a_bso[cc]);
        tsig[idx] = sigmoidf_(sc[5 * 1056] + t_bso[cc]);
    }
    __syncthreads();

    // ---- phase 4: K=128 GEMMs. waves 0-3: qkvg from AH; 4-7: w1/w2 from TH ----
    {
        const float* W;
        const float* xs;
        int ldw, sel2 = 0, cb = 0;
        if (wave < 4) {
            W = (wave == 0 ? wq : wave == 1 ? wk : wave == 2 ? wv : wg) + c0;
            xs = smem + AN_OFF;
            ldw = 128;
        } else {
            const int u = (wave - 4) * 128 + c0;
            sel2 = u >> 8; cb = u & 255;
            W = (sel2 ? w2 : w1) + cb;
            xs = smem + TH_OFF;
            ldw = 256;
        }
        float acc0[8], acc1[8];
        #pragma unroll
        for (int e = 0; e < 8; e++) {
            const float init = (wave == 0) ? bq[c0 + e] : 0.f;
            acc0[e] = init; acc1[e] = init;
        }
        for (int kk = 0; kk < 128; kk += 4) {
            float4 x40 = *(const float4*)(xs + r0 * 132 + kk);
            float4 x41 = *(const float4*)(xs + r1 * 132 + kk);
            #pragma unroll
            for (int q = 0; q < 4; q++) {
                const float4 wlo = *(const float4*)(W + (kk + q) * ldw);
                const float4 whi = *(const float4*)(W + (kk + q) * ldw + 4);
                const float xa = ((const float*)&x40)[q];
                const float xb = ((const float*)&x41)[q];
                acc0[0] += xa * wlo.x; acc0[1] += xa * wlo.y;
                acc0[2] += xa * wlo.z; acc0[3] += xa * wlo.w;
                acc0[4] += xa * whi.x; acc0[5] += xa * whi.y;
                acc0[6] += xa * whi.z; acc0[7] += xa * whi.w;
                acc1[0] += xb * wlo.x; acc1[1] += xb * wlo.y;
                acc1[2] += xb * wlo.z; acc1[3] += xb * wlo.w;
                acc1[4] += xb * whi.x; acc1[5] += xb * whi.y;
                acc1[6] += xb * whi.z; acc1[7] += xb * whi.w;
            }
        }
        if (wave < 4) {
            float* dst = (wave == 0 ? qh : wave == 1 ? kh : wave == 2 ? vh : gh);
            if (wave == 3) {
                #pragma unroll
                for (int e = 0; e < 8; e++) {
                    acc0[e] = sigmoidf_(acc0[e]);
                    acc1[e] = sigmoidf_(acc1[e]);
                }
            }
            *(float4*)(dst + (base + r0) * 128 + c0)     = make_float4(acc0[0], acc0[1], acc0[2], acc0[3]);
            *(float4*)(dst + (base + r0) * 128 + c0 + 4) = make_float4(acc0[4], acc0[5], acc0[6], acc0[7]);
            *(float4*)(dst + (base + r1) * 128 + c0)     = make_float4(acc1[0], acc1[1], acc1[2], acc1[3]);
            *(float4*)(dst + (base + r1) * 128 + c0 + 4) = make_float4(acc1[4], acc1[5], acc1[6], acc1[7]);
        } else {
            float* bsc = smem + SCR_OFF + sel2 * 2080;
            *(float4*)(bsc + r0 * 260 + cb)     = make_float4(acc0[0], acc0[1], acc0[2], acc0[3]);
            *(float4*)(bsc + r0 * 260 + cb + 4) = make_float4(acc0[4], acc0[5], acc0[6], acc0[7]);
            *(float4*)(bsc + r1 * 260 + cb)     = make_float4(acc1[0], acc1[1], acc1[2], acc1[3]);
            *(float4*)(bsc + r1 * 260 + cb + 4) = make_float4(acc1[4], acc1[5], acc1[6], acc1[7]);
        }
    }
    __syncthreads();

    // ---- phase 4c: bm = silu(a1) * a2 ----
    #pragma unroll
    for (int i2 = 0; i2 < 4; i2++) {
        const int e = t + i2 * 512;       // 2048 = 8 rows x 256 cols
        const int r = e >> 8, cc = e & 255;
        const float a1 = smem[SCR_OFF + r * 260 + cc];
        const float a2 = smem[SCR_OFF + 2080 + r * 260 + cc];
        bm[(base + r) * 256 + cc] = a1 * sigmoidf_(a1) * a2;
    }
}

// ---------------------------------------------------------------------------
// k_cpre: FUSED combine(i) + pre(i+1). 512 threads, 8 rows/block, grid 512.
// Phase A: 8-wave K-split combine GEMVs (wo: waves 0-3 K=32 each; wout:
//          waves 4-7 K=64 each) -> LDS partials. (old k_combine was 2
//          waves/SIMD; this runs the same FMAs at 4 waves/SIMD)
// Phase B: reduce partials -> a = asig*so + tsig*st, kept ONLY in LDS
//          (abuf HBM round-trip eliminated).
// Phases C..G: identical pipeline to k_pre phases 1..4c, with `a` sourced
//          from LDS. asig/tsig/c prefetched at entry to hide latency.
// ---------------------------------------------------------------------------
#define C_AN 0
#define C_TH 1056
#define C_SA 2112
#define C_ST 2656
#define C_CR 3200
#define C_SCR 3744
#define C_SMEM (3744 + 8448)   // 12192 floats = 47.6 KB

__global__ __launch_bounds__(512, 4) void k_cpre(
    const float* __restrict__ og, float* __restrict__ bmio,
    const float* __restrict__ wo, const float* __restrict__ wout,
    float* __restrict__ asig, float* __restrict__ tsig,
    const float* __restrict__ c,
    const float* __restrict__ a_sg, const float* __restrict__ a_gw,
    const float* __restrict__ a_sw, const float* __restrict__ a_wso,
    const float* __restrict__ a_bso,
    const float* __restrict__ t_sg, const float* __restrict__ t_gw,
    const float* __restrict__ t_sw, const float* __restrict__ t_wso,
    const float* __restrict__ t_bso,
    const float* __restrict__ wq, const float* __restrict__ bq,
    const float* __restrict__ wk, const float* __restrict__ wv,
    const float* __restrict__ wg,
    const float* __restrict__ w1, const float* __restrict__ w2,
    float* __restrict__ qh, float* __restrict__ kh,
    float* __restrict__ vh, float* __restrict__ gh)
{
    __shared__ float smem[C_SMEM];
    const int t = threadIdx.x;
    const int base = blockIdx.x * 8;
    const int wave = t >> 6, lane = t & 63;
    const int ig = lane >> 4, jc = lane & 15;
    const int c0 = jc * 8;
    const int r0 = ig * 2, r1 = r0 + 1;

    // ---- prefetch: phase-C inputs (c row) + phase-B gates (iter-i asig/tsig)
    const int rloc = wave, li = lane;
    const float cv  = c[(base + rloc) * 64 + li];
    const float sgA = a_sg[li], sgT = t_sg[li];
    const int e1 = t + 512;
    const int br0 = t >> 7,  bc0 = t & 127;
    const int br1 = e1 >> 7, bc1 = e1 & 127;
    const int gidx0 = (base + br0) * 128 + bc0;
    const int gidx1 = (base + br1) * 128 + bc1;
    const float as0 = asig[gidx0], ts0 = tsig[gidx0];
    const float as1 = asig[gidx1], ts1 = tsig[gidx1];

    // ---- phase A: combine GEMVs, 8-wave K-split ----
    {
        float acc0[8], acc1[8];
        #pragma unroll
        for (int e = 0; e < 8; e++) { acc0[e] = 0.f; acc1[e] = 0.f; }
        if (wave < 4) {
            const float* W = wo + c0;
            const float* X = og + base * 128;
            const int kbeg = wave * 32;
            for (int kk = kbeg; kk < kbeg + 32; kk += 4) {
                float4 x40 = *(const float4*)(X + r0 * 128 + kk);
                float4 x41 = *(const float4*)(X + r1 * 128 + kk);
                #pragma unroll
                for (int q = 0; q < 4; q++) {
                    const float4 wlo = *(const float4*)(W + (kk + q) * 128);
                    const float4 whi = *(const float4*)(W + (kk + q) * 128 + 4);
                    const float xa = ((const float*)&x40)[q];
                    const float xb = ((const float*)&x41)[q];
                    acc0[0] += xa * wlo.x; acc0[1] += xa * wlo.y;
                    acc0[2] += xa * wlo.z; acc0[3] += xa * wlo.w;
                    acc0[4] += xa * whi.x; acc0[5] += xa * whi.y;
                    acc0[6] += xa * whi.z; acc0[7] += xa * whi.w;
                    acc1[0] += xb * wlo.x; acc1[1] += xb * wlo.y;
                    acc1[2] += xb * wlo.z; acc1[3] += xb * wlo.w;
                    acc1[4] += xb * whi.x; acc1[5] += xb * whi.y;
                    acc1[6] += xb * whi.z; acc1[7] += xb * whi.w;
                }
            }
        } else {
            const float* W = wout + c0;
            const float* X = bmio + base * 256;
            const int kbeg = (wave - 4) * 64;
            for (int kk = kbeg; kk < kbeg + 64; kk += 4) {
                float4 x40 = *(const float4*)(X + r0 * 256 + kk);
                float4 x41 = *(const float4*)(X + r1 * 256 + kk);
                #pragma unroll
                for (int q = 0; q < 4; q++) {
                    const float4 wlo = *(const float4*)(W + (kk + q) * 128);
                    const float4 whi = *(const float4*)(W + (kk + q) * 128 + 4);
                    const float xa = ((const float*)&x40)[q];
                    const float xb = ((const float*)&x41)[q];
                    acc0[0] += xa * wlo.x; acc0[1] += xa * wlo.y;
                    acc0[2] += xa * wlo.z; acc0[3] += xa * wlo.w;
                    acc0[4] += xa * whi.x; acc0[5] += xa * whi.y;
                    acc0[6] += xa * whi.z; acc0[7] += xa * whi.w;
                    acc1[0] += xb * wlo.x; acc1[1] += xb * wlo.y;
                    acc1[2] += xb * wlo.z; acc1[3] += xb * wlo.w;
                    acc1[4] += xb * whi.x; acc1[5] += xb * whi.y;
                    acc1[6] += xb * whi.z; acc1[7] += xb * whi.w;
                }
            }
        }
        float* sc = smem + C_SCR + wave * 1056;
        *(float4*)(sc + r0 * 132 + c0)     = make_float4(acc0[0], acc0[1], acc0[2], acc0[3]);
        *(float4*)(sc + r0 * 132 + c0 + 4) = make_float4(acc0[4], acc0[5], acc0[6], acc0[7]);
        *(float4*)(sc + r1 * 132 + c0)     = make_float4(acc1[0], acc1[1], acc1[2], acc1[3]);
        *(float4*)(sc + r1 * 132 + c0 + 4) = make_float4(acc1[4], acc1[5], acc1[6], acc1[7]);
    }
    __syncthreads();

    // ---- phase B: reduce partials -> raw a into AN (LDS only) ----
    {
        const float* s0 = smem + C_SCR + br0 * 132 + bc0;
        const float so0 = s0[0] + s0[1056] + s0[2112] + s0[3168];
        const float st0 = s0[4224] + s0[5280] + s0[6336] + s0[7392];
        smem[C_AN + br0 * 132 + bc0] = as0 * so0 + ts0 * st0;
        const float* s1 = smem + C_SCR + br1 * 132 + bc1;
        const float so1 = s1[0] + s1[1056] + s1[2112] + s1[3168];
        const float st1 = s1[4224] + s1[5280] + s1[6336] + s1[7392];
        smem[C_AN + br1 * 132 + bc1] = as1 * so1 + ts1 * st1;
    }
    __syncthreads();

    // ---- phase C: LN stats, a from LDS, c prefetched ----
    {
        float2 av = *(const float2*)&smem[C_AN + rloc * 132 + li * 2];
        float s = av.x + av.y;
        float ss = av.x * av.x + av.y * av.y;
        float cs = cv, css = cv * cv;
        #pragma unroll
        for (int m = 1; m < 64; m <<= 1) {
            s += __shfl_xor(s, m);
            ss += __shfl_xor(ss, m);
            cs += __shfl_xor(cs, m);
            css += __shfl_xor(css, m);
        }
        const float am = s * (1.0f / 128.0f);
        const float ars = rsqrtf(ss * (1.0f / 128.0f) - am * am + 1e-5f);
        const float cm = cs * (1.0f / 64.0f);
        const float crs = rsqrtf(css * (1.0f / 64.0f) - cm * cm + 1e-5f);
        smem[C_AN + rloc * 132 + li * 2]     = (av.x - am) * ars;
        smem[C_AN + rloc * 132 + li * 2 + 1] = (av.y - am) * ars;
        const float cn = (cv - cm) * crs;
        smem[C_SA + rloc * 68 + li] = cn * sgA;
        smem[C_ST + rloc * 68 + li] = cn * sgT;
        smem[C_CR + rloc * 68 + li] = cv;
    }
    __syncthreads();

    // ---- phase D: six K=64 GEMVs (waves 0..5) ----
    if (wave < 6) {
        const float* W;
        const float* xs;
        switch (wave) {
            case 0: W = a_gw;  xs = smem + C_SA; break;
            case 1: W = a_sw;  xs = smem + C_SA; break;
            case 2: W = t_gw;  xs = smem + C_ST; break;
            case 3: W = t_sw;  xs = smem + C_ST; break;
            case 4: W = a_wso; xs = smem + C_CR; break;
            default: W = t_wso; xs = smem + C_CR; break;
        }
        W += c0;
        float acc0[8], acc1[8];
        #pragma unroll
        for (int e = 0; e < 8; e++) { acc0[e] = 0.f; acc1[e] = 0.f; }
        for (int kk = 0; kk < 64; kk += 4) {
            float4 x40 = *(const float4*)(xs + r0 * 68 + kk);
            float4 x41 = *(const float4*)(xs + r1 * 68 + kk);
            #pragma unroll
            for (int q = 0; q < 4; q++) {
                const float4 wlo = *(const float4*)(W + (kk + q) * 128);
                const float4 whi = *(const float4*)(W + (kk + q) * 128 + 4);
                const float xa = ((const float*)&x40)[q];
                const float xb = ((const float*)&x41)[q];
                acc0[0] += xa * wlo.x; acc0[1] += xa * wlo.y;
                acc0[2] += xa * wlo.z; acc0[3] += xa * wlo.w;
                acc0[4] += xa * whi.x; acc0[5] += xa * whi.y;
                acc0[6] += xa * whi.z; acc0[7] += xa * whi.w;
                acc1[0] += xb * wlo.x; acc1[1] += xb * wlo.y;
                acc1[2] += xb * wlo.z; acc1[3] += xb * wlo.w;
                acc1[4] += xb * whi.x; acc1[5] += xb * whi.y;
                acc1[6] += xb * whi.z; acc1[7] += xb * whi.w;
            }
        }
        float* sc = smem + C_SCR + wave * 1056;
        *(float4*)(sc + r0 * 132 + c0)     = make_float4(acc0[0], acc0[1], acc0[2], acc0[3]);
        *(float4*)(sc + r0 * 132 + c0 + 4) = make_float4(acc0[4], acc0[5], acc0[6], acc0[7]);
        *(float4*)(sc + r1 * 132 + c0)     = make_float4(acc1[0], acc1[1], acc1[2], acc1[3]);
        *(float4*)(sc + r1 * 132 + c0 + 4) = make_float4(acc1[4], acc1[5], acc1[6], acc1[7]);
    }
    __syncthreads();

    // ---- phase E: combine -> ah (in-place over AN), th, asig/tsig (i+1) ----
    #pragma unroll
    for (int i2 = 0; i2 < 2; i2++) {
        const int e = t + i2 * 512;
        const int r = e >> 7, cc = e & 127;
        const float* sc = smem + C_SCR + r * 132 + cc;
        const float anv = smem[C_AN + r * 132 + cc];
        const float ahv = sigmoidf_(sc[0]) * anv + sc[1056];
        const float thv = sigmoidf_(sc[2 * 1056]) * anv + sc[3 * 1056];
        smem[C_AN + r * 132 + cc] = ahv;
        smem[C_TH + r * 132 + cc] = thv;
        const int idx = (base + r) * 128 + cc;
        asig[idx] = sigmoidf_(sc[4 * 1056] + a_bso[cc]);
        tsig[idx] = sigmoidf_(sc[5 * 1056] + t_bso[cc]);
    }
    __syncthreads();

    // ---- phase F: K=128 GEMMs (waves 0-3: qkvg; 4-7: w1/w2) ----
    {
        const float* W;
        const float* xs;
        int ldw, sel2 = 0, cb = 0;
        if (wave < 4) {
            W = (wave == 0 ? wq : wave == 1 ? wk : wave == 2 ? wv : wg) + c0;
            xs = smem + C_AN;
            ldw = 128;
        } else {
            const int u = (wave - 4) * 128 + c0;
            sel2 = u >> 8; cb = u & 255;
            W = (sel2 ? w2 : w1) + cb;
            xs = smem + C_TH;
            ldw = 256;
        }
        float acc0[8], acc1[8];
        #pragma unroll
        for (int e = 0; e < 8; e++) {
            const float init = (wave == 0) ? bq[c0 + e] : 0.f;
            acc0[e] = init; acc1[e] = init;
        }
        for (int kk = 0; kk < 128; kk += 4) {
            float4 x40 = *(const float4*)(xs + r0 * 132 + kk);
            float4 x41 = *(const float4*)(xs + r1 * 132 + kk);
            #pragma unroll
            for (int q = 0; q < 4; q++) {
                const float4 wlo = *(const float4*)(W + (kk + q) * ldw);
                const float4 whi = *(const float4*)(W + (kk + q) * ldw + 4);
                const float xa = ((const float*)&x40)[q];
                const float xb = ((const float*)&x41)[q];
                acc0[0] += xa * wlo.x; acc0[1] += xa * wlo.y;
                acc0[2] += xa * wlo.z; acc0[3] += xa * wlo.w;
                acc0[4] += xa * whi.x; acc0[5] += xa * whi.y;
                acc0[6] += xa * whi.z; acc0[7] += xa * whi.w;
                acc1[0] += xb * wlo.x; acc1[1] += xb * wlo.y;
                acc1[2] += xb * wlo.z; acc1[3] += xb * wlo.w;
                acc1[4] += xb * whi.x; acc1[5] += xb * whi.y;
                acc1[6] += xb * whi.z; acc1[7] += xb * whi.w;
            }
        }
        if (wave < 4) {
            float* dst = (wave == 0 ? qh : wave == 1 ? kh : wave == 2 ? vh : gh);
            if (wave == 3) {
                #pragma unroll
                for (int e = 0; e < 8; e++) {
                    acc0[e] = sigmoidf_(acc0[e]);
                    acc1[e] = sigmoidf_(acc1[e]);
                }
            }
            *(float4*)(dst + (base + r0) * 128 + c0)     = make_float4(acc0[0], acc0[1], acc0[2], acc0[3]);
            *(float4*)(dst + (base + r0) * 128 + c0 + 4) = make_float4(acc0[4], acc0[5], acc0[6], acc0[7]);
            *(float4*)(dst + (base + r1) * 128 + c0)     = make_float4(acc1[0], acc1[1], acc1[2], acc1[3]);
            *(float4*)(dst + (base + r1) * 128 + c0 + 4) = make_float4(acc1[4], acc1[5], acc1[6], acc1[7]);
        } else {
            float* bsc = smem + C_SCR + sel2 * 2080;
            *(float4*)(bsc + r0 * 260 + cb)     = make_float4(acc0[0], acc0[1], acc0[2], acc0[3]);
            *(float4*)(bsc + r0 * 260 + cb + 4) = make_float4(acc0[4], acc0[5], acc0[6], acc0[7]);
            *(float4*)(bsc + r1 * 260 + cb)     = make_float4(acc1[0], acc1[1], acc1[2], acc1[3]);
            *(float4*)(bsc + r1 * 260 + cb + 4) = make_float4(acc1[4], acc1[5], acc1[6], acc1[7]);
        }
    }
    __syncthreads();

    // ---- phase G: bm = silu(a1) * a2 (overwrites bmio; rows block-private) ----
    #pragma unroll
    for (int i2 = 0; i2 < 4; i2++) {
        const int e = t + i2 * 512;
        const int r = e >> 8, cc = e & 255;
        const float a1 = smem[C_SCR + r * 260 + cc];
        const float a2 = smem[C_SCR + 2080 + r * 260 + cc];
        bmio[(base + r) * 256 + cc] = a1 * sigmoidf_(a1) * a2;
    }
}

// ---------------------------------------------------------------------------
// k_fin: final combine -> d_out. 512 threads, 8-wave K-split (wo: waves 0-3
// K=32; wout: waves 4-7 K=64). 2x the wave-occupancy of the old k_combine.
// ---------------------------------------------------------------------------
__global__ __launch_bounds__(512, 4) void k_fin(
    const float* __restrict__ og, const float* __restrict__ bm,
    const float* __restrict__ wo, const float* __restrict__ wout,
    const float* __restrict__ asig, const float* __restrict__ tsig,
    float* __restrict__ out)
{
    __shared__ float scr[8 * 1056];
    const int t = threadIdx.x;
    const int base = blockIdx.x * 8;
    const int wave = t >> 6, lane = t & 63;
    const int ig = lane >> 4, jc = lane & 15;
    const int c0 = jc * 8;
    const int r0 = ig * 2, r1 = r0 + 1;

    const int e1 = t + 512;
    const int br0 = t >> 7,  bc0 = t & 127;
    const int br1 = e1 >> 7, bc1 = e1 & 127;
    const int gidx0 = (base + br0) * 128 + bc0;
    const int gidx1 = (base + br1) * 128 + bc1;
    const float as0 = asig[gidx0], ts0 = tsig[gidx0];
    const float as1 = asig[gidx1], ts1 = tsig[gidx1];

    float acc0[8], acc1[8];
    #pragma unroll
    for (int e = 0; e < 8; e++) { acc0[e] = 0.f; acc1[e] = 0.f; }

    if (wave < 4) {
        const float* W = wo + c0;
        const float* X = og + base * 128;
        const int kbeg = wave * 32;
        for (int kk = kbeg; kk < kbeg + 32; kk += 4) {
            float4 x40 = *(const float4*)(X + r0 * 128 + kk);
            float4 x41 = *(const float4*)(X + r1 * 128 + kk);
            #pragma unroll
            for (int q = 0; q < 4; q++) {
                const float4 wlo = *(const float4*)(W + (kk + q) * 128);
                const float4 whi = *(const float4*)(W + (kk + q) * 128 + 4);
                const float xa = ((const float*)&x40)[q];
                const float xb = ((const float*)&x41)[q];
                acc0[0] += xa * wlo.x; acc0[1] += xa * wlo.y;
                acc0[2] += xa * wlo.z; acc0[3] += xa * wlo.w;
                acc0[4] += xa * whi.x; acc0[5] += xa * whi.y;
                acc0[6] += xa * whi.z; acc0[7] += xa * whi.w;
                acc1[0] += xb * wlo.x; acc1[1] += xb * wlo.y;
                acc1[2] += xb * wlo.z; acc1[3] += xb * wlo.w;
                acc1[4] += xb * whi.x; acc1[5] += xb * whi.y;
                acc1[6] += xb * whi.z; acc1[7] += xb * whi.w;
            }
        }
    } else {
        const float* W = wout + c0;
        const float* X = bm + base * 256;
        const int kbeg = (wave - 4) * 64;
        for (int kk = kbeg; kk < kbeg + 64; kk += 4) {
            float4 x40 = *(const float4*)(X + r0 * 256 + kk);
            float4 x41 = *(const float4*)(X + r1 * 256 + kk);
            #pragma unroll
            for (int q = 0; q < 4; q++) {
                const float4 wlo = *(const float4*)(W + (kk + q) * 128);
                const float4 whi = *(const float4*)(W + (kk + q) * 128 + 4);
                const float xa = ((const float*)&x40)[q];
                const float xb = ((const float*)&x41)[q];
                acc0[0] += xa * wlo.x; acc0[1] += xa * wlo.y;
                acc0[2] += xa * wlo.z; acc0[3] += xa * wlo.w;
                acc0[4] += xa * whi.x; acc0[5] += xa * whi.y;
                acc0[6] += xa * whi.z; acc0[7] += xa * whi.w;
                acc1[0] += xb * wlo.x; acc1[1] += xb * wlo.y;
                acc1[2] += xb * wlo.z; acc1[3] += xb * wlo.w;
                acc1[4] += xb * whi.x; acc1[5] += xb * whi.y;
                acc1[6] += xb * whi.z; acc1[7] += xb * whi.w;
            }
        }
    }
    float* sc = scr + wave * 1056;
    *(float4*)(sc + r0 * 132 + c0)     = make_float4(acc0[0], acc0[1], acc0[2], acc0[3]);
    *(float4*)(sc + r0 * 132 + c0 + 4) = make_float4(acc0[4], acc0[5], acc0[6], acc0[7]);
    *(float4*)(sc + r1 * 132 + c0)     = make_float4(acc1[0], acc1[1], acc1[2], acc1[3]);
    *(float4*)(sc + r1 * 132 + c0 + 4) = make_float4(acc1[4], acc1[5], acc1[6], acc1[7]);
    __syncthreads();

    {
        const float* s0 = scr + br0 * 132 + bc0;
        out[gidx0] = as0 * (s0[0] + s0[1056] + s0[2112] + s0[3168])
                   + ts0 * (s0[4224] + s0[5280] + s0[6336] + s0[7392]);
        const float* s1 = scr + br1 * 132 + bc1;
        out[gidx1] = as1 * (s1[0] + s1[1056] + s1[2112] + s1[3168])
                   + ts1 * (s1[4224] + s1[5280] + s1[6336] + s1[7392]);
    }
}

// ---------------------------------------------------------------------------
// k_zbias: z-bias for all 3 blocks in one pass. zb layout [NB][R][H][KW].
// ---------------------------------------------------------------------------
__global__ __launch_bounds__(256) void k_zbias(
    const float* __restrict__ p,
    const float* __restrict__ lnz_g, const float* __restrict__ lnz_b,
    const float* __restrict__ wb, float* __restrict__ zb)
{
    const int tid = blockIdx.x * 256 + threadIdx.x;
    const int kk = tid & 127;
    const int n = (tid >> 7) & 1023;
    const int b = tid >> 17;
    const int row = b * N_ + n;
    const int k = ((n >> 5) << 5) - 48 + kk;

    if (k < 0 || k >= N_) {
        #pragma unroll
        for (int blk = 0; blk < NB_; blk++) {
            float* zo = zb + ((size_t)(blk * R_ + row) * H_) * KW_ + kk;
            #pragma unroll
            for (int h = 0; h < H_; h++) zo[h * KW_] = -1e10f;
        }
        return;
    }
    const float* pp = p + ((size_t)row * N_ + k) * CP_;
    float pv[16];
    float4 p0 = *(const float4*)(pp);
    float4 p1 = *(const float4*)(pp + 4);
    float4 p2 = *(const float4*)(pp + 8);
    float4 p3 = *(const float4*)(pp + 12);
    pv[0]=p0.x; pv[1]=p0.y; pv[2]=p0.z; pv[3]=p0.w;
    pv[4]=p1.x; pv[5]=p1.y; pv[6]=p1.z; pv[7]=p1.w;
    pv[8]=p2.x; pv[9]=p2.y; pv[10]=p2.z; pv[11]=p2.w;
    pv[12]=p3.x; pv[13]=p3.y; pv[14]=p3.z; pv[15]=p3.w;
    float s = 0.f, ss = 0.f;
    #pragma unroll
    for (int i = 0; i < 16; i++) { s += pv[i]; ss += pv[i] * pv[i]; }
    const float m = s * (1.0f / 16.0f);
    const float rs = rsqrtf(ss * (1.0f / 16.0f) - m * m + 1e-5f);

    #pragma unroll
    for (int blk = 0; blk < NB_; blk++) {
        const float* g = lnz_g + blk * 16;
        const float* bb = lnz_b + blk * 16;
        const float* w = wb + blk * 64;
        float z0 = 0.f, z1 = 0.f, z2 = 0.f, z3 = 0.f;
        #pragma unroll
        for (int cp = 0; cp < 16; cp++) {
            const float val = (pv[cp] - m) * rs * g[cp] + bb[cp];
            z0 += val * w[cp * 4 + 0];
            z1 += val * w[cp * 4 + 1];
            z2 += val * w[cp * 4 + 2];
            z3 += val * w[cp * 4 + 3];
        }
        float* zo = zb + ((size_t)(blk * R_ + row) * H_) * KW_ + kk;
        zo[0] = z0; zo[KW_] = z1; zo[2 * KW_] = z2; zo[3 * KW_] = z3;
    }
}

// ---------------------------------------------------------------------------
// k_attn: 32 queries x 128-key window. grid (32, H, B), 256 threads.
// (verified round-1 version, unchanged)
// ---------------------------------------------------------------------------
__global__ __launch_bounds__(256) void k_attn(
    const float* __restrict__ qh, const float* __restrict__ kh,
    const float* __restrict__ vh, const float* __restrict__ gh,
    const float* __restrict__ zb, float* __restrict__ og)
{
    __shared__ float kT[32][136];
    __shared__ float vs[128][36];
    __shared__ float wsm[32][132];

    const int t = threadIdx.x;
    const int qb = blockIdx.x, h = blockIdx.y, b = blockIdx.z;
    const int k0 = qb * 32 - 48;

    #pragma unroll
    for (int i = 0; i < 4; i++) {
        const int e = t + i * 256;
        const int kk = e >> 3, d4 = (e & 7) * 4;
        const int kg = k0 + kk;
        float4 kv = make_float4(0.f, 0.f, 0.f, 0.f);
        float4 vv = make_float4(0.f, 0.f, 0.f, 0.f);
        if (kg >= 0 && kg < N_) {
            const int addr = (b * N_ + kg) * 128 + h * 32 + d4;
            kv = *(const float4*)(kh + addr);
            vv = *(const float4*)(vh + addr);
        }
        kT[d4 + 0][kk] = kv.x;
        kT[d4 + 1][kk] = kv.y;
        kT[d4 + 2][kk] = kv.z;
        kT[d4 + 3][kk] = kv.w;
        *(float4*)&vs[kk][d4] = vv;
    }

    const int q = t >> 3, j = t & 7;
    const int n = qb * 32 + q;
    const float* qrow = qh + (b * N_ + n) * 128 + h * 32;
    float4 qf[8];
    #pragma unroll
    for (int dq = 0; dq < 8; dq++) qf[dq] = *(const float4*)(qrow + dq * 4);
    const float* zrow = zb + ((size_t)(b * N_ + n) * H_ + h) * KW_;
    float4 zf[4];
    #pragma unroll
    for (int g4 = 0; g4 < 4; g4++) zf[g4] = *(const float4*)(zrow + g4 * 32 + j * 4);
    __syncthreads();

    float4 acc[4];
    #pragma unroll
    for (int g4 = 0; g4 < 4; g4++) acc[g4] = make_float4(0.f, 0.f, 0.f, 0.f);
    const float* qfs = (const float*)qf;
    #pragma unroll
    for (int d = 0; d < 32; d++) {
        const float qd = qfs[d];
        #pragma unroll
        for (int g4 = 0; g4 < 4; g4++) {
            const float4 k4 = *(const float4*)&kT[d][g4 * 32 + j * 4];
            acc[g4].x += qd * k4.x; acc[g4].y += qd * k4.y;
            acc[g4].z += qd * k4.z; acc[g4].w += qd * k4.w;
        }
    }
    const float scale = 0.1767766952966369f;
    float fr[16];
    #pragma unroll
    for (int g4 = 0; g4 < 4; g4++) {
        fr[g4*4+0] = zf[g4].x + acc[g4].x * scale;
        fr[g4*4+1] = zf[g4].y + acc[g4].y * scale;
        fr[g4*4+2] = zf[g4].z + acc[g4].z * scale;
        fr[g4*4+3] = zf[g4].w + acc[g4].w * scale;
    }
    float mx = fr[0];
    #pragma unroll
    for (int i = 1; i < 16; i++) mx = fmaxf(mx, fr[i]);
    #pragma unroll
    for (int mk = 1; mk < 8; mk <<= 1) mx = fmaxf(mx, __shfl_xor(mx, mk));
    float sum = 0.f;
    #pragma unroll
    for (int i = 0; i < 16; i++) { fr[i] = __expf(fr[i] - mx); sum += fr[i]; }
    #pragma unroll
    for (int mk = 1; mk < 8; mk <<= 1) sum += __shfl_xor(sum, mk);
    const float rinv = 1.0f / sum;
    #pragma unroll
    for (int g4 = 0; g4 < 4; g4++) {
        *(float4*)&wsm[q][g4 * 32 + j * 4] = make_float4(
            fr[g4*4+0] * rinv, fr[g4*4+1] * rinv,
            fr[g4*4+2] * rinv, fr[g4*4+3] * rinv);
    }
    asm volatile("s_waitcnt lgkmcnt(0)" ::: "memory");

    const int addrO = (b * N_ + n) * 128 + h * 32 + j * 4;
    const float4 g4v = *(const float4*)(gh + addrO);
    float4 o = make_float4(0.f, 0.f, 0.f, 0.f);
    #pragma unroll 4
    for (int kk = 0; kk < 128; kk += 4) {
        const float4 w4 = *(const float4*)&wsm[q][kk];
        const float4 v0 = *(const float4*)&vs[kk + 0][j * 4];
        const float4 v1 = *(const float4*)&vs[kk + 1][j * 4];
        const float4 v2 = *(const float4*)&vs[kk + 2][j * 4];
        const float4 v3 = *(const float4*)&vs[kk + 3][j * 4];
        o.x += w4.x * v0.x + w4.y * v1.x + w4.z * v2.x + w4.w * v3.x;
        o.y += w4.x * v0.y + w4.y * v1.y + w4.z * v2.y + w4.w * v3.y;
        o.z += w4.x * v0.z + w4.y * v1.z + w4.z * v2.z + w4.w * v3.z;
        o.w += w4.x * v0.w + w4.y * v1.w + w4.z * v2.w + w4.w * v3.w;
    }
    float4 outv;
    outv.x = o.x * g4v.x; outv.y = o.y * g4v.y;
    outv.z = o.z * g4v.z; outv.w = o.w * g4v.w;
    *(float4*)(og + addrO) = outv;
}

// ---------------------------------------------------------------------------
extern "C" void kernel_launch(void* const* d_in, const int* in_sizes, int n_in,
                              void* d_out, int out_size, void* d_ws, size_t ws_size,
                              hipStream_t stream)
{
    const float* q        = (const float*)d_in[0];
    const float* c        = (const float*)d_in[1];
    const float* p        = (const float*)d_in[2];
    const float* a_sg_all = (const float*)d_in[3];
    const float* a_gw_all = (const float*)d_in[4];
    const float* a_sw_all = (const float*)d_in[5];
    const float* wq_all   = (const float*)d_in[6];
    const float* bq_all   = (const float*)d_in[7];
    const float* wk_all   = (const float*)d_in[8];
    const float* wv_all   = (const float*)d_in[9];
    const float* lnzg_all = (const float*)d_in[10];
    const float* lnzb_all = (const float*)d_in[11];
    const float* wb_all   = (const float*)d_in[12];
    const float* wgt_all  = (const float*)d_in[13];
    const float* wo_all   = (const float*)d_in[14];
    const float* awso_all = (const float*)d_in[15];
    const float* abso_all = (const float*)d_in[16];
    const float* t_sg_all = (const float*)d_in[17];
    const float* t_gw_all = (const float*)d_in[18];
    const float* t_sw_all = (const float*)d_in[19];
    const float* w1_all   = (const float*)d_in[20];
    const float* w2_all   = (const float*)d_in[21];
    const float* wout_all = (const float*)d_in[22];
    const float* twso_all = (const float*)d_in[23];
    const float* tbso_all = (const float*)d_in[24];

    float* ws = (float*)d_ws;
    const size_t RC = (size_t)R_ * CQ_;   // 524288
    float* qh   = ws;
    float* kh   = ws + RC;
    float* vh   = ws + 2 * RC;
    float* gh   = ws + 3 * RC;
    float* bmb  = ws + 4 * RC;            // R*256 = 2*RC
    float* asig = ws + 6 * RC;
    float* tsig = ws + 7 * RC;
    float* ogb  = ws + 8 * RC;
    float* zbb  = ws + 9 * RC;            // NB*R*H*KW = 12*RC

    k_zbias<<<dim3(B_ * N_ * KW_ / 256), dim3(256), 0, stream>>>(
        p, lnzg_all, lnzb_all, wb_all, zbb);

    // iter 0: pre from input q
    k_pre<<<dim3(R_ / 8), dim3(512), 0, stream>>>(
        q, c,
        a_sg_all, a_gw_all, a_sw_all, awso_all, abso_all,
        t_sg_all, t_gw_all, t_sw_all, twso_all, tbso_all,
        wq_all, bq_all, wk_all, wv_all, wgt_all,
        w1_all, w2_all,
        qh, kh, vh, gh, bmb, asig, tsig);

    for (int blk = 0; blk < NB_; blk++) {
        k_attn<<<dim3(N_ / 32, H_, B_), dim3(256), 0, stream>>>(
            qh, kh, vh, gh, zbb + (size_t)blk * R_ * H_ * KW_, ogb);
        if (blk < NB_ - 1) {
            const int nx = blk + 1;
            k_cpre<<<dim3(R_ / 8), dim3(512), 0, stream>>>(
                ogb, bmb,
                wo_all + blk * CQ_ * CQ_, wout_all + blk * 2 * CQ_ * CQ_,
                asig, tsig, c,
                a_sg_all + nx * CKV_, a_gw_all + nx * CKV_ * CQ_,
                a_sw_all + nx * CKV_ * CQ_, awso_all + nx * CKV_ * CQ_,
                abso_all + nx * CQ_,
                t_sg_all + nx * CKV_, t_gw_all + nx * CKV_ * CQ_,
                t_sw_all + nx * CKV_ * CQ_, twso_all + nx * CKV_ * CQ_,
                tbso_all + nx * CQ_,
                wq_all + nx * CQ_ * CQ_, bq_all + nx * CQ_,
                wk_all + nx * CQ_ * CQ_, wv_all + nx * CQ_ * CQ_,
                wgt_all + nx * CQ_ * CQ_,
                w1_all + nx * CQ_ * 2 * CQ_, w2_all + nx * CQ_ * 2 * CQ_,
                qh, kh, vh, gh);
        } else {
            k_fin<<<dim3(R_ / 8), dim3(512), 0, stream>>>(
                ogb, bmb,
                wo_all + blk * CQ_ * CQ_, wout_all + blk * 2 * CQ_ * CQ_,
                asig, tsig, (float*)d_out);
        }
    }
}